// Round 1
// baseline (3123.656 us; speedup 1.0000x reference)
//
#include <hip/hip_runtime.h>
#include <hip/hip_bf16.h>
#include <stdint.h>

#define EDIM 1024
#define DFFDIM 4096
#define NLAYER 4
#define BATCH 4
#define SEQ 1024
#define NHEAD 16
#define DHEAD 64
#define VOCAB 32000
#define MROWS (BATCH*SEQ)
#define EPSF 1e-6f

typedef float f32x4 __attribute__((ext_vector_type(4)));
typedef short s16x8 __attribute__((ext_vector_type(8)));
typedef __bf16 bf16x8 __attribute__((ext_vector_type(8)));

__device__ inline unsigned short f2bf(float f) {
  union { float f; uint32_t u; } v; v.f = f;
  uint32_t r = v.u + 0x7fffu + ((v.u >> 16) & 1u);
  return (unsigned short)(r >> 16);
}

// ---------------- embedding + positional encoding ----------------
__global__ __launch_bounds__(256) void embed_kernel(
    const int* __restrict__ tokens, const float* __restrict__ emb,
    const float* __restrict__ pe, float* __restrict__ x,
    unsigned short* __restrict__ xb) {
  const int row = blockIdx.x;          // b*SEQ + s
  const int s = row & (SEQ - 1);
  const int tok = tokens[row];
  const int c = threadIdx.x * 4;
  float4 ev = *(const float4*)(emb + (size_t)tok * EDIM + c);
  float4 pv = *(const float4*)(pe + (size_t)s * EDIM + c);
  float4 o;
  o.x = ev.x + pv.x; o.y = ev.y + pv.y; o.z = ev.z + pv.z; o.w = ev.w + pv.w;
  *(float4*)(x + (size_t)row * EDIM + c) = o;
  unsigned short* xr = xb + (size_t)row * EDIM + c;
  xr[0] = f2bf(o.x); xr[1] = f2bf(o.y); xr[2] = f2bf(o.z); xr[3] = f2bf(o.w);
}

// ---------------- generic GEMM: C[M,N] = A_bf16[M,K] @ W_f32[K,N] + bias ----------------
// 128x128 tile, BK=32, 4 waves (2x2), each wave 64x64 via 4x4 16x16x32 MFMA frags.
template<int OUT_BF16, int RELU>
__global__ __launch_bounds__(256) void gemm_kernel(
    const unsigned short* __restrict__ A, const float* __restrict__ W,
    const float* __restrict__ bias, void* __restrict__ Cout,
    int Nld, int K) {
  const int n0 = blockIdx.x * 128, m0 = blockIdx.y * 128;
  const int t = threadIdx.x, lane = t & 63;
  const int wave = t >> 6, wr = wave >> 1, wc = wave & 1;
  const int l15 = lane & 15, lg = lane >> 4;
  __shared__ unsigned short Asm[128][40];   // [m][k], +8 pad breaks bank conflicts
  __shared__ unsigned short Bsm[128][40];   // [n][k] (transposed W tile)

  f32x4 acc[4][4];
  #pragma unroll
  for (int i = 0; i < 4; ++i)
    #pragma unroll
    for (int j = 0; j < 4; ++j)
      acc[i][j] = (f32x4){0.f, 0.f, 0.f, 0.f};

  const int ar = t >> 1, ac = (t & 1) * 16;       // A staging: 128 rows x 32 cols
  const int bkr = t >> 3, bc0 = (t & 7) * 16;     // B staging: 32 k-rows x 128 n-cols

  for (int k0 = 0; k0 < K; k0 += 32) {
    const unsigned short* ap = A + (size_t)(m0 + ar) * K + k0 + ac;
    *(s16x8*)&Asm[ar][ac]     = *(const s16x8*)ap;
    *(s16x8*)&Asm[ar][ac + 8] = *(const s16x8*)(ap + 8);

    const float* wp = W + (size_t)(k0 + bkr) * Nld + n0 + bc0;
    #pragma unroll
    for (int i = 0; i < 16; i += 4) {
      float4 wv = *(const float4*)(wp + i);
      Bsm[bc0 + i + 0][bkr] = f2bf(wv.x);
      Bsm[bc0 + i + 1][bkr] = f2bf(wv.y);
      Bsm[bc0 + i + 2][bkr] = f2bf(wv.z);
      Bsm[bc0 + i + 3][bkr] = f2bf(wv.w);
    }
    __syncthreads();

    bf16x8 af[4], bfr[4];
    #pragma unroll
    for (int mf = 0; mf < 4; ++mf)
      af[mf] = *(const bf16x8*)&Asm[wr * 64 + mf * 16 + l15][lg * 8];
    #pragma unroll
    for (int nf = 0; nf < 4; ++nf)
      bfr[nf] = *(const bf16x8*)&Bsm[wc * 64 + nf * 16 + l15][lg * 8];
    #pragma unroll
    for (int mf = 0; mf < 4; ++mf)
      #pragma unroll
      for (int nf = 0; nf < 4; ++nf)
        acc[mf][nf] = __builtin_amdgcn_mfma_f32_16x16x32_bf16(af[mf], bfr[nf], acc[mf][nf], 0, 0, 0);
    __syncthreads();
  }

  #pragma unroll
  for (int mf = 0; mf < 4; ++mf) {
    #pragma unroll
    for (int nf = 0; nf < 4; ++nf) {
      const int col = n0 + wc * 64 + nf * 16 + l15;
      const float bv = bias[col];
      #pragma unroll
      for (int r = 0; r < 4; ++r) {
        const int row = m0 + wr * 64 + mf * 16 + lg * 4 + r;
        float val = acc[mf][nf][r] + bv;
        if (RELU) val = fmaxf(val, 0.f);
        if (OUT_BF16)
          ((unsigned short*)Cout)[(size_t)row * Nld + col] = f2bf(val);
        else
          ((float*)Cout)[(size_t)row * Nld + col] = val;
      }
    }
  }
}

// ---------------- flash attention: per wave 16 q-rows, KV tiles of 32 ----------------
__global__ __launch_bounds__(256) void attn_kernel(
    const unsigned short* __restrict__ q, const unsigned short* __restrict__ k,
    const unsigned short* __restrict__ v, unsigned short* __restrict__ ctx) {
  const int b = blockIdx.z, h = blockIdx.y;
  const int wave = threadIdx.x >> 6, lane = threadIdx.x & 63;
  const int l15 = lane & 15, lg = lane >> 4;
  const int qrow0 = blockIdx.x * 64 + wave * 16;
  const size_t base = (size_t)b * SEQ * EDIM + h * DHEAD;
  __shared__ unsigned short p_lds[4][16][40];

  const unsigned short* qp = q + base + (size_t)(qrow0 + l15) * EDIM + lg * 8;
  bf16x8 a0 = *(const bf16x8*)qp;
  bf16x8 a1 = *(const bf16x8*)(qp + 32);

  f32x4 o0 = {0,0,0,0}, o1 = {0,0,0,0}, o2 = {0,0,0,0}, o3 = {0,0,0,0};
  float m[4], ls[4];
  #pragma unroll
  for (int r = 0; r < 4; ++r) { m[r] = -1e30f; ls[r] = 0.f; }

  const unsigned short* kb = k + base;
  const unsigned short* vb = v + base;

  for (int j = 0; j < SEQ / 32; ++j) {
    const int kv0 = j * 32;
    const unsigned short* kp = kb + (size_t)(kv0 + l15) * EDIM + lg * 8;
    bf16x8 b00 = *(const bf16x8*)kp;
    bf16x8 b01 = *(const bf16x8*)(kp + 32);
    bf16x8 b10 = *(const bf16x8*)(kp + (size_t)16 * EDIM);
    bf16x8 b11 = *(const bf16x8*)(kp + (size_t)16 * EDIM + 32);
    f32x4 s0 = {0,0,0,0}, s1 = {0,0,0,0};
    s0 = __builtin_amdgcn_mfma_f32_16x16x32_bf16(a0, b00, s0, 0, 0, 0);
    s0 = __builtin_amdgcn_mfma_f32_16x16x32_bf16(a1, b01, s0, 0, 0, 0);
    s1 = __builtin_amdgcn_mfma_f32_16x16x32_bf16(a0, b10, s1, 0, 0, 0);
    s1 = __builtin_amdgcn_mfma_f32_16x16x32_bf16(a1, b11, s1, 0, 0, 0);

    float mx[4], p0[4], p1[4], scl[4], rs[4];
    #pragma unroll
    for (int r = 0; r < 4; ++r) { s0[r] *= 0.125f; s1[r] *= 0.125f; mx[r] = fmaxf(s0[r], s1[r]); }
    #pragma unroll
    for (int off = 1; off < 16; off <<= 1) {
      #pragma unroll
      for (int r = 0; r < 4; ++r) mx[r] = fmaxf(mx[r], __shfl_xor(mx[r], off));
    }
    #pragma unroll
    for (int r = 0; r < 4; ++r) {
      const float mn = fmaxf(m[r], mx[r]);
      scl[r] = __expf(m[r] - mn);
      m[r] = mn;
      p0[r] = __expf(s0[r] - mn);
      p1[r] = __expf(s1[r] - mn);
      rs[r] = p0[r] + p1[r];
    }
    #pragma unroll
    for (int off = 1; off < 16; off <<= 1) {
      #pragma unroll
      for (int r = 0; r < 4; ++r) rs[r] += __shfl_xor(rs[r], off);
    }
    #pragma unroll
    for (int r = 0; r < 4; ++r) {
      ls[r] = ls[r] * scl[r] + rs[r];
      o0[r] *= scl[r]; o1[r] *= scl[r]; o2[r] *= scl[r]; o3[r] *= scl[r];
      p_lds[wave][lg * 4 + r][l15]      = f2bf(p0[r]);
      p_lds[wave][lg * 4 + r][16 + l15] = f2bf(p1[r]);
    }
    bf16x8 pa = *(const bf16x8*)&p_lds[wave][l15][lg * 8];

    s16x8 bv0, bv1, bv2, bv3;
    #pragma unroll
    for (int e = 0; e < 8; ++e) {
      const unsigned short* vr = vb + (size_t)(kv0 + lg * 8 + e) * EDIM;
      bv0[e] = (short)vr[l15];
      bv1[e] = (short)vr[16 + l15];
      bv2[e] = (short)vr[32 + l15];
      bv3[e] = (short)vr[48 + l15];
    }
    union { s16x8 s; bf16x8 b; } u0{bv0}, u1{bv1}, u2{bv2}, u3{bv3};
    o0 = __builtin_amdgcn_mfma_f32_16x16x32_bf16(pa, u0.b, o0, 0, 0, 0);
    o1 = __builtin_amdgcn_mfma_f32_16x16x32_bf16(pa, u1.b, o1, 0, 0, 0);
    o2 = __builtin_amdgcn_mfma_f32_16x16x32_bf16(pa, u2.b, o2, 0, 0, 0);
    o3 = __builtin_amdgcn_mfma_f32_16x16x32_bf16(pa, u3.b, o3, 0, 0, 0);
  }

  unsigned short* cp = ctx + base;
  #pragma unroll
  for (int r = 0; r < 4; ++r) {
    unsigned short* cr = cp + (size_t)(qrow0 + lg * 4 + r) * EDIM;
    const float inv = 1.f / ls[r];
    cr[l15]      = f2bf(o0[r] * inv);
    cr[16 + l15] = f2bf(o1[r] * inv);
    cr[32 + l15] = f2bf(o2[r] * inv);
    cr[48 + l15] = f2bf(o3[r] * inv);
  }
}

// ---------------- residual + layernorm: x = x + LN(a); writes f32 x and bf16 xb ----------------
__global__ __launch_bounds__(256) void ln_add_kernel(
    const float* __restrict__ a, const float* __restrict__ g, const float* __restrict__ bb,
    float* __restrict__ x, unsigned short* __restrict__ xb) {
  const int row = blockIdx.x, t = threadIdx.x;
  const float* ar = a + (size_t)row * EDIM;
  float4 av = *(const float4*)(ar + t * 4);
  float s = av.x + av.y + av.z + av.w;
  float qq = av.x * av.x + av.y * av.y + av.z * av.z + av.w * av.w;
  #pragma unroll
  for (int off = 1; off < 64; off <<= 1) { s += __shfl_xor(s, off); qq += __shfl_xor(qq, off); }
  __shared__ float red[8];
  const int wv = t >> 6;
  if ((t & 63) == 0) { red[wv] = s; red[4 + wv] = qq; }
  __syncthreads();
  s = red[0] + red[1] + red[2] + red[3];
  qq = red[4] + red[5] + red[6] + red[7];
  const float mean = s * (1.f / EDIM);
  const float rstd = rsqrtf(qq * (1.f / EDIM) - mean * mean + EPSF);
  float4 gv = *(const float4*)(g + t * 4);
  float4 bv = *(const float4*)(bb + t * 4);
  float* xr = x + (size_t)row * EDIM;
  float4 xv = *(float4*)(xr + t * 4);
  float4 o;
  o.x = xv.x + (av.x - mean) * rstd * gv.x + bv.x;
  o.y = xv.y + (av.y - mean) * rstd * gv.y + bv.y;
  o.z = xv.z + (av.z - mean) * rstd * gv.z + bv.z;
  o.w = xv.w + (av.w - mean) * rstd * gv.w + bv.w;
  *(float4*)(xr + t * 4) = o;
  unsigned short* xbr = xb + (size_t)row * EDIM + t * 4;
  xbr[0] = f2bf(o.x); xbr[1] = f2bf(o.y); xbr[2] = f2bf(o.z); xbr[3] = f2bf(o.w);
}

// ---------------- final double layernorm -> bf16 ----------------
__global__ __launch_bounds__(256) void final_ln_kernel(
    const float* __restrict__ x, const float* __restrict__ g1, const float* __restrict__ b1,
    const float* __restrict__ g2, const float* __restrict__ b2,
    unsigned short* __restrict__ xb) {
  const int row = blockIdx.x, t = threadIdx.x;
  __shared__ float red[8];
  const int wv = t >> 6;
  const float* xr = x + (size_t)row * EDIM;
  float4 v = *(const float4*)(xr + t * 4);

  float s = v.x + v.y + v.z + v.w;
  float qq = v.x * v.x + v.y * v.y + v.z * v.z + v.w * v.w;
  #pragma unroll
  for (int off = 1; off < 64; off <<= 1) { s += __shfl_xor(s, off); qq += __shfl_xor(qq, off); }
  if ((t & 63) == 0) { red[wv] = s; red[4 + wv] = qq; }
  __syncthreads();
  s = red[0] + red[1] + red[2] + red[3];
  qq = red[4] + red[5] + red[6] + red[7];
  __syncthreads();
  float mean = s * (1.f / EDIM);
  float rstd = rsqrtf(qq * (1.f / EDIM) - mean * mean + EPSF);
  float4 g1v = *(const float4*)(g1 + t * 4);
  float4 b1v = *(const float4*)(b1 + t * 4);
  float4 tv;
  tv.x = (v.x - mean) * rstd * g1v.x + b1v.x;
  tv.y = (v.y - mean) * rstd * g1v.y + b1v.y;
  tv.z = (v.z - mean) * rstd * g1v.z + b1v.z;
  tv.w = (v.w - mean) * rstd * g1v.w + b1v.w;

  s = tv.x + tv.y + tv.z + tv.w;
  qq = tv.x * tv.x + tv.y * tv.y + tv.z * tv.z + tv.w * tv.w;
  #pragma unroll
  for (int off = 1; off < 64; off <<= 1) { s += __shfl_xor(s, off); qq += __shfl_xor(qq, off); }
  if ((t & 63) == 0) { red[wv] = s; red[4 + wv] = qq; }
  __syncthreads();
  s = red[0] + red[1] + red[2] + red[3];
  qq = red[4] + red[5] + red[6] + red[7];
  mean = s * (1.f / EDIM);
  rstd = rsqrtf(qq * (1.f / EDIM) - mean * mean + EPSF);
  float4 g2v = *(const float4*)(g2 + t * 4);
  float4 b2v = *(const float4*)(b2 + t * 4);
  unsigned short* o = xb + (size_t)row * EDIM + t * 4;
  o[0] = f2bf((tv.x - mean) * rstd * g2v.x + b2v.x);
  o[1] = f2bf((tv.y - mean) * rstd * g2v.y + b2v.y);
  o[2] = f2bf((tv.z - mean) * rstd * g2v.z + b2v.z);
  o[3] = f2bf((tv.w - mean) * rstd * g2v.w + b2v.w);
}

// ---------------- launch ----------------
extern "C" void kernel_launch(void* const* d_in, const int* in_sizes, int n_in,
                              void* d_out, int out_size, void* d_ws, size_t ws_size,
                              hipStream_t stream) {
  const int*   tokens = (const int*)d_in[0];
  const float* emb    = (const float*)d_in[1];
  const float* pe     = (const float*)d_in[2];
  const float* Wq     = (const float*)d_in[3];
  const float* Wk     = (const float*)d_in[4];
  const float* Wv     = (const float*)d_in[5];
  const float* Wo     = (const float*)d_in[6];
  const float* W1     = (const float*)d_in[7];
  const float* W2     = (const float*)d_in[8];
  const float* bq     = (const float*)d_in[9];
  const float* bk     = (const float*)d_in[10];
  const float* bv     = (const float*)d_in[11];
  const float* bo     = (const float*)d_in[12];
  const float* b1     = (const float*)d_in[13];
  const float* b2     = (const float*)d_in[14];
  const float* ln1_g  = (const float*)d_in[15];
  const float* ln1_b  = (const float*)d_in[16];
  const float* ln2_g  = (const float*)d_in[17];
  const float* ln2_b  = (const float*)d_in[18];
  const float* enc_g  = (const float*)d_in[19];
  const float* enc_b  = (const float*)d_in[20];
  const float* fin_g  = (const float*)d_in[21];
  const float* fin_b  = (const float*)d_in[22];
  const float* Wout   = (const float*)d_in[23];
  const float* bout   = (const float*)d_in[24];
  float* out = (float*)d_out;

  uint8_t* p = (uint8_t*)d_ws;
  auto alloc = [&](size_t bytes) {
    void* r = (void*)p;
    p += (bytes + 255) & ~(size_t)255;
    return r;
  };
  float*          x    = (float*)alloc((size_t)MROWS * EDIM * 4);
  unsigned short* xb   = (unsigned short*)alloc((size_t)MROWS * EDIM * 2);
  unsigned short* qb   = (unsigned short*)alloc((size_t)MROWS * EDIM * 2);
  unsigned short* kb   = (unsigned short*)alloc((size_t)MROWS * EDIM * 2);
  unsigned short* vbuf = (unsigned short*)alloc((size_t)MROWS * EDIM * 2);
  unsigned short* ctx  = (unsigned short*)alloc((size_t)MROWS * EDIM * 2);
  float*          tbuf = (float*)alloc((size_t)MROWS * EDIM * 4);
  unsigned short* ff1  = (unsigned short*)alloc((size_t)MROWS * DFFDIM * 2);
  if ((size_t)(p - (uint8_t*)d_ws) > ws_size) return;  // insufficient workspace -> fail loudly

  const dim3 blk(256);
  embed_kernel<<<MROWS, blk, 0, stream>>>(tokens, emb, pe, x, xb);

  for (int i = 0; i < NLAYER; ++i) {
    const size_t wOff = (size_t)i * EDIM * EDIM;
    gemm_kernel<1, 0><<<dim3(EDIM / 128, MROWS / 128), blk, 0, stream>>>(
        xb, Wq + wOff, bq + i * EDIM, qb, EDIM, EDIM);
    gemm_kernel<1, 0><<<dim3(EDIM / 128, MROWS / 128), blk, 0, stream>>>(
        xb, Wk + wOff, bk + i * EDIM, kb, EDIM, EDIM);
    gemm_kernel<1, 0><<<dim3(EDIM / 128, MROWS / 128), blk, 0, stream>>>(
        xb, Wv + wOff, bv + i * EDIM, vbuf, EDIM, EDIM);
    attn_kernel<<<dim3(SEQ / 64, NHEAD, BATCH), blk, 0, stream>>>(qb, kb, vbuf, ctx);
    gemm_kernel<0, 0><<<dim3(EDIM / 128, MROWS / 128), blk, 0, stream>>>(
        ctx, Wo + wOff, bo + i * EDIM, tbuf, EDIM, EDIM);
    ln_add_kernel<<<MROWS, blk, 0, stream>>>(tbuf, ln1_g + i * EDIM, ln1_b + i * EDIM, x, xb);
    gemm_kernel<1, 1><<<dim3(DFFDIM / 128, MROWS / 128), blk, 0, stream>>>(
        xb, W1 + (size_t)i * EDIM * DFFDIM, b1 + i * DFFDIM, ff1, DFFDIM, EDIM);
    gemm_kernel<0, 0><<<dim3(EDIM / 128, MROWS / 128), blk, 0, stream>>>(
        ff1, W2 + (size_t)i * DFFDIM * EDIM, b2 + i * EDIM, tbuf, EDIM, DFFDIM);
    ln_add_kernel<<<MROWS, blk, 0, stream>>>(tbuf, ln2_g + i * EDIM, ln2_b + i * EDIM, x, xb);
  }

  final_ln_kernel<<<MROWS, blk, 0, stream>>>(x, enc_g, enc_b, fin_g, fin_b, xb);
  gemm_kernel<0, 0><<<dim3(VOCAB / 128, MROWS / 128), blk, 0, stream>>>(
      xb, Wout, bout, out, VOCAB, EDIM);
}

// Round 3
// 2430.046 us; speedup vs baseline: 1.2854x; 1.2854x over previous
//
#include <hip/hip_runtime.h>
#include <hip/hip_bf16.h>
#include <stdint.h>

#define EDIM 1024
#define DFFDIM 4096
#define NLAYER 4
#define BATCH 4
#define SEQ 1024
#define NHEAD 16
#define DHEAD 64
#define VOCAB 32000
#define MROWS (BATCH*SEQ)
#define EPSF 1e-6f

typedef float f32x4 __attribute__((ext_vector_type(4)));
typedef short s16x8 __attribute__((ext_vector_type(8)));
typedef __bf16 bf16x8 __attribute__((ext_vector_type(8)));

__device__ inline unsigned short f2bf(float f) {
  union { float f; uint32_t u; } v; v.f = f;
  uint32_t r = v.u + 0x7fffu + ((v.u >> 16) & 1u);
  return (unsigned short)(r >> 16);
}

__device__ __forceinline__ void gload16(const void* g, void* l) {
  __builtin_amdgcn_global_load_lds(
      (const __attribute__((address_space(1))) void*)g,
      (__attribute__((address_space(3))) void*)l, 16, 0, 0);
}

// ---------------- embedding + positional encoding ----------------
__global__ __launch_bounds__(256) void embed_kernel(
    const int* __restrict__ tokens, const float* __restrict__ emb,
    const float* __restrict__ pe, float* __restrict__ x,
    unsigned short* __restrict__ xb) {
  const int row = blockIdx.x;
  const int s = row & (SEQ - 1);
  const int tok = tokens[row];
  const int c = threadIdx.x * 4;
  float4 ev = *(const float4*)(emb + (size_t)tok * EDIM + c);
  float4 pv = *(const float4*)(pe + (size_t)s * EDIM + c);
  float4 o;
  o.x = ev.x + pv.x; o.y = ev.y + pv.y; o.z = ev.z + pv.z; o.w = ev.w + pv.w;
  *(float4*)(x + (size_t)row * EDIM + c) = o;
  unsigned short* xr = xb + (size_t)row * EDIM + c;
  xr[0] = f2bf(o.x); xr[1] = f2bf(o.y); xr[2] = f2bf(o.z); xr[3] = f2bf(o.w);
}

// ---------------- weight transpose+convert: src f32 [K,N] -> dst bf16 [N,K] ----------------
__global__ __launch_bounds__(256) void transpose_w(
    const float* __restrict__ src, unsigned short* __restrict__ dst,
    int N, int K) {
  __shared__ float tl[64][65];
  const int t = threadIdx.x;
  const int k0 = blockIdx.x * 64, n0 = blockIdx.y * 64;
  const int c = (t & 15) * 4, r0 = t >> 4;
  #pragma unroll
  for (int i = 0; i < 4; ++i) {
    const int r = r0 + i * 16;
    float4 v = *(const float4*)(src + (size_t)(k0 + r) * N + n0 + c);
    tl[r][c] = v.x; tl[r][c + 1] = v.y; tl[r][c + 2] = v.z; tl[r][c + 3] = v.w;
  }
  __syncthreads();
  #pragma unroll
  for (int i = 0; i < 4; ++i) {
    const int n = r0 + i * 16;
    uint2 o;
    o.x = (uint32_t)f2bf(tl[c + 0][n]) | ((uint32_t)f2bf(tl[c + 1][n]) << 16);
    o.y = (uint32_t)f2bf(tl[c + 2][n]) | ((uint32_t)f2bf(tl[c + 3][n]) << 16);
    *(uint2*)(dst + (size_t)(n0 + n) * K + k0 + c) = o;
  }
}

// ---------------- m97-structure GEMM: C[M,N] = A_bf16[M,K] @ Bt_bf16[N,K] + bias ----------------
// 128x128 tile, BK=32, 4 waves (2x2), global_load_lds width=16, linear LDS.
template<int OUT_BF16, int RELU>
__global__ __launch_bounds__(256) void gemm_bt(
    const unsigned short* __restrict__ A, const unsigned short* __restrict__ Bt,
    const float* __restrict__ bias, void* __restrict__ Cout,
    int Nld, int K, int MBLK) {
  __shared__ unsigned short sm[2 * 128 * 32];   // A tile 8KB | B tile 8KB, linear
  const int t = threadIdx.x, lane = t & 63;
  const int wave = t >> 6, wr = wave >> 1, wc = wave & 1;
  const int l15 = lane & 15, lg = lane >> 4;

  // bijective XCD swizzle (gridDim.x % 8 == 0 for all our shapes)
  const int cpx = gridDim.x >> 3;
  const int bid = blockIdx.x;
  const int swz = (bid & 7) * cpx + (bid >> 3);
  const int m0 = (swz % MBLK) * 128;
  const int n0 = (swz / MBLK) * 128;

  f32x4 acc[4][4];
  #pragma unroll
  for (int i = 0; i < 4; ++i)
    #pragma unroll
    for (int j = 0; j < 4; ++j)
      acc[i][j] = (f32x4){0.f, 0.f, 0.f, 0.f};

  // staging: per wave 2 chunks of 16 rows x 32 cols for A, same for B
  const int ca = wave * 2;
  const int srow = ca * 16 + (lane >> 2);
  const int scol = (lane & 3) * 8;
  const unsigned short* agp = A + (size_t)(m0 + srow) * K + scol;
  const unsigned short* bgp = Bt + (size_t)(n0 + srow) * K + scol;
  unsigned short* lA = &sm[(size_t)srow * 32 + scol];            // == ca*512 + lane*8
  unsigned short* lB = &sm[4096 + (size_t)srow * 32 + scol];
  const size_t rstep = (size_t)16 * K;

  for (int k0 = 0; k0 < K; k0 += 32) {
    gload16(agp + k0, lA);
    gload16(agp + rstep + k0, lA + 16 * 32);
    gload16(bgp + k0, lB);
    gload16(bgp + rstep + k0, lB + 16 * 32);
    __syncthreads();

    bf16x8 af[4], bfr[4];
    #pragma unroll
    for (int mf = 0; mf < 4; ++mf)
      af[mf] = *(const bf16x8*)&sm[(wr * 64 + mf * 16 + l15) * 32 + lg * 8];
    #pragma unroll
    for (int nf = 0; nf < 4; ++nf)
      bfr[nf] = *(const bf16x8*)&sm[4096 + (wc * 64 + nf * 16 + l15) * 32 + lg * 8];
    #pragma unroll
    for (int mf = 0; mf < 4; ++mf)
      #pragma unroll
      for (int nf = 0; nf < 4; ++nf)
        acc[mf][nf] = __builtin_amdgcn_mfma_f32_16x16x32_bf16(af[mf], bfr[nf], acc[mf][nf], 0, 0, 0);
    __syncthreads();
  }

  #pragma unroll
  for (int mf = 0; mf < 4; ++mf) {
    #pragma unroll
    for (int nf = 0; nf < 4; ++nf) {
      const int col = n0 + wc * 64 + nf * 16 + l15;
      const float bv = bias[col];
      #pragma unroll
      for (int r = 0; r < 4; ++r) {
        const int row = m0 + wr * 64 + mf * 16 + lg * 4 + r;
        float val = acc[mf][nf][r] + bv;
        if (RELU) val = fmaxf(val, 0.f);
        if (OUT_BF16)
          ((unsigned short*)Cout)[(size_t)row * Nld + col] = f2bf(val);
        else
          ((float*)Cout)[(size_t)row * Nld + col] = val;
      }
    }
  }
}

// ---------------- flash attention: K/V^T cooperatively staged in LDS ----------------
__global__ __launch_bounds__(256) void attn_kernel(
    const unsigned short* __restrict__ q, const unsigned short* __restrict__ k,
    const unsigned short* __restrict__ v, unsigned short* __restrict__ ctx) {
  const int b = blockIdx.z, h = blockIdx.y;
  const int t = threadIdx.x, wave = t >> 6, lane = t & 63;
  const int l15 = lane & 15, lg = lane >> 4;
  const int qrow0 = blockIdx.x * 64 + wave * 16;
  const size_t base = (size_t)b * SEQ * EDIM + h * DHEAD;
  __shared__ unsigned short Ksm[32][72];   // 32 kv x 64 d (+8 pad): rows are 64 wide!
  __shared__ unsigned short VT[64][40];    // 64 d x 32 kv (+8 pad)
  __shared__ unsigned short p_lds[4][16][40];

  const unsigned short* qp = q + base + (size_t)(qrow0 + l15) * EDIM + lg * 8;
  bf16x8 a0 = *(const bf16x8*)qp;
  bf16x8 a1 = *(const bf16x8*)(qp + 32);

  f32x4 o0 = {0,0,0,0}, o1 = {0,0,0,0}, o2 = {0,0,0,0}, o3 = {0,0,0,0};
  float m[4], ls[4];
  #pragma unroll
  for (int r = 0; r < 4; ++r) { m[r] = -1e30f; ls[r] = 0.f; }

  const unsigned short* kb = k + base;
  const unsigned short* vb = v + base;
  const int sr = t >> 3;            // kv row 0..31
  const int sc = (t & 7) * 8;       // d col 0..56

  for (int j = 0; j < SEQ / 32; ++j) {
    const int kv0 = j * 32;
    // cooperative staging: K rows, V transposed
    s16x8 kv8 = *(const s16x8*)(kb + (size_t)(kv0 + sr) * EDIM + sc);
    *(s16x8*)&Ksm[sr][sc] = kv8;
    s16x8 vv8 = *(const s16x8*)(vb + (size_t)(kv0 + sr) * EDIM + sc);
    #pragma unroll
    for (int e = 0; e < 8; ++e) VT[sc + e][sr] = (unsigned short)vv8[e];
    __syncthreads();

    bf16x8 b00 = *(const bf16x8*)&Ksm[l15][lg * 8];
    bf16x8 b01 = *(const bf16x8*)&Ksm[l15][32 + lg * 8];
    bf16x8 b10 = *(const bf16x8*)&Ksm[16 + l15][lg * 8];
    bf16x8 b11 = *(const bf16x8*)&Ksm[16 + l15][32 + lg * 8];
    f32x4 s0 = {0,0,0,0}, s1 = {0,0,0,0};
    s0 = __builtin_amdgcn_mfma_f32_16x16x32_bf16(a0, b00, s0, 0, 0, 0);
    s0 = __builtin_amdgcn_mfma_f32_16x16x32_bf16(a1, b01, s0, 0, 0, 0);
    s1 = __builtin_amdgcn_mfma_f32_16x16x32_bf16(a0, b10, s1, 0, 0, 0);
    s1 = __builtin_amdgcn_mfma_f32_16x16x32_bf16(a1, b11, s1, 0, 0, 0);

    float mx[4], p0[4], p1[4], scl[4], rs[4];
    #pragma unroll
    for (int r = 0; r < 4; ++r) { s0[r] *= 0.125f; s1[r] *= 0.125f; mx[r] = fmaxf(s0[r], s1[r]); }
    #pragma unroll
    for (int off = 1; off < 16; off <<= 1) {
      #pragma unroll
      for (int r = 0; r < 4; ++r) mx[r] = fmaxf(mx[r], __shfl_xor(mx[r], off));
    }
    #pragma unroll
    for (int r = 0; r < 4; ++r) {
      const float mn = fmaxf(m[r], mx[r]);
      scl[r] = __expf(m[r] - mn);
      m[r] = mn;
      p0[r] = __expf(s0[r] - mn);
      p1[r] = __expf(s1[r] - mn);
      rs[r] = p0[r] + p1[r];
    }
    #pragma unroll
    for (int off = 1; off < 16; off <<= 1) {
      #pragma unroll
      for (int r = 0; r < 4; ++r) rs[r] += __shfl_xor(rs[r], off);
    }
    #pragma unroll
    for (int r = 0; r < 4; ++r) {
      ls[r] = ls[r] * scl[r] + rs[r];
      o0[r] *= scl[r]; o1[r] *= scl[r]; o2[r] *= scl[r]; o3[r] *= scl[r];
      p_lds[wave][lg * 4 + r][l15]      = f2bf(p0[r]);
      p_lds[wave][lg * 4 + r][16 + l15] = f2bf(p1[r]);
    }
    bf16x8 pa = *(const bf16x8*)&p_lds[wave][l15][lg * 8];

    bf16x8 v0 = *(const bf16x8*)&VT[l15][lg * 8];
    bf16x8 v1 = *(const bf16x8*)&VT[16 + l15][lg * 8];
    bf16x8 v2 = *(const bf16x8*)&VT[32 + l15][lg * 8];
    bf16x8 v3 = *(const bf16x8*)&VT[48 + l15][lg * 8];
    o0 = __builtin_amdgcn_mfma_f32_16x16x32_bf16(pa, v0, o0, 0, 0, 0);
    o1 = __builtin_amdgcn_mfma_f32_16x16x32_bf16(pa, v1, o1, 0, 0, 0);
    o2 = __builtin_amdgcn_mfma_f32_16x16x32_bf16(pa, v2, o2, 0, 0, 0);
    o3 = __builtin_amdgcn_mfma_f32_16x16x32_bf16(pa, v3, o3, 0, 0, 0);
    __syncthreads();
  }

  unsigned short* cp = ctx + base;
  #pragma unroll
  for (int r = 0; r < 4; ++r) {
    unsigned short* cr = cp + (size_t)(qrow0 + lg * 4 + r) * EDIM;
    const float inv = 1.f / ls[r];
    cr[l15]      = f2bf(o0[r] * inv);
    cr[16 + l15] = f2bf(o1[r] * inv);
    cr[32 + l15] = f2bf(o2[r] * inv);
    cr[48 + l15] = f2bf(o3[r] * inv);
  }
}

// ---------------- residual + layernorm ----------------
__global__ __launch_bounds__(256) void ln_add_kernel(
    const float* __restrict__ a, const float* __restrict__ g, const float* __restrict__ bb,
    float* __restrict__ x, unsigned short* __restrict__ xb) {
  const int row = blockIdx.x, t = threadIdx.x;
  const float* ar = a + (size_t)row * EDIM;
  float4 av = *(const float4*)(ar + t * 4);
  float s = av.x + av.y + av.z + av.w;
  float qq = av.x * av.x + av.y * av.y + av.z * av.z + av.w * av.w;
  #pragma unroll
  for (int off = 1; off < 64; off <<= 1) { s += __shfl_xor(s, off); qq += __shfl_xor(qq, off); }
  __shared__ float red[8];
  const int wv = t >> 6;
  if ((t & 63) == 0) { red[wv] = s; red[4 + wv] = qq; }
  __syncthreads();
  s = red[0] + red[1] + red[2] + red[3];
  qq = red[4] + red[5] + red[6] + red[7];
  const float mean = s * (1.f / EDIM);
  const float rstd = rsqrtf(qq * (1.f / EDIM) - mean * mean + EPSF);
  float4 gv = *(const float4*)(g + t * 4);
  float4 bv = *(const float4*)(bb + t * 4);
  float* xr = x + (size_t)row * EDIM;
  float4 xv = *(float4*)(xr + t * 4);
  float4 o;
  o.x = xv.x + (av.x - mean) * rstd * gv.x + bv.x;
  o.y = xv.y + (av.y - mean) * rstd * gv.y + bv.y;
  o.z = xv.z + (av.z - mean) * rstd * gv.z + bv.z;
  o.w = xv.w + (av.w - mean) * rstd * gv.w + bv.w;
  *(float4*)(xr + t * 4) = o;
  unsigned short* xbr = xb + (size_t)row * EDIM + t * 4;
  xbr[0] = f2bf(o.x); xbr[1] = f2bf(o.y); xbr[2] = f2bf(o.z); xbr[3] = f2bf(o.w);
}

// ---------------- final double layernorm -> bf16 ----------------
__global__ __launch_bounds__(256) void final_ln_kernel(
    const float* __restrict__ x, const float* __restrict__ g1, const float* __restrict__ b1,
    const float* __restrict__ g2, const float* __restrict__ b2,
    unsigned short* __restrict__ xb) {
  const int row = blockIdx.x, t = threadIdx.x;
  __shared__ float red[8];
  const int wv = t >> 6;
  const float* xr = x + (size_t)row * EDIM;
  float4 v = *(const float4*)(xr + t * 4);

  float s = v.x + v.y + v.z + v.w;
  float qq = v.x * v.x + v.y * v.y + v.z * v.z + v.w * v.w;
  #pragma unroll
  for (int off = 1; off < 64; off <<= 1) { s += __shfl_xor(s, off); qq += __shfl_xor(qq, off); }
  if ((t & 63) == 0) { red[wv] = s; red[4 + wv] = qq; }
  __syncthreads();
  s = red[0] + red[1] + red[2] + red[3];
  qq = red[4] + red[5] + red[6] + red[7];
  __syncthreads();
  float mean = s * (1.f / EDIM);
  float rstd = rsqrtf(qq * (1.f / EDIM) - mean * mean + EPSF);
  float4 g1v = *(const float4*)(g1 + t * 4);
  float4 b1v = *(const float4*)(b1 + t * 4);
  float4 tv;
  tv.x = (v.x - mean) * rstd * g1v.x + b1v.x;
  tv.y = (v.y - mean) * rstd * g1v.y + b1v.y;
  tv.z = (v.z - mean) * rstd * g1v.z + b1v.z;
  tv.w = (v.w - mean) * rstd * g1v.w + b1v.w;

  s = tv.x + tv.y + tv.z + tv.w;
  qq = tv.x * tv.x + tv.y * tv.y + tv.z * tv.z + tv.w * tv.w;
  #pragma unroll
  for (int off = 1; off < 64; off <<= 1) { s += __shfl_xor(s, off); qq += __shfl_xor(qq, off); }
  if ((t & 63) == 0) { red[wv] = s; red[4 + wv] = qq; }
  __syncthreads();
  s = red[0] + red[1] + red[2] + red[3];
  qq = red[4] + red[5] + red[6] + red[7];
  mean = s * (1.f / EDIM);
  rstd = rsqrtf(qq * (1.f / EDIM) - mean * mean + EPSF);
  float4 g2v = *(const float4*)(g2 + t * 4);
  float4 b2v = *(const float4*)(b2 + t * 4);
  unsigned short* o = xb + (size_t)row * EDIM + t * 4;
  o[0] = f2bf((tv.x - mean) * rstd * g2v.x + b2v.x);
  o[1] = f2bf((tv.y - mean) * rstd * g2v.y + b2v.y);
  o[2] = f2bf((tv.z - mean) * rstd * g2v.z + b2v.z);
  o[3] = f2bf((tv.w - mean) * rstd * g2v.w + b2v.w);
}

// ---------------- launch ----------------
extern "C" void kernel_launch(void* const* d_in, const int* in_sizes, int n_in,
                              void* d_out, int out_size, void* d_ws, size_t ws_size,
                              hipStream_t stream) {
  const int*   tokens = (const int*)d_in[0];
  const float* emb    = (const float*)d_in[1];
  const float* pe     = (const float*)d_in[2];
  const float* Wq     = (const float*)d_in[3];
  const float* Wk     = (const float*)d_in[4];
  const float* Wv     = (const float*)d_in[5];
  const float* Wo     = (const float*)d_in[6];
  const float* W1     = (const float*)d_in[7];
  const float* W2     = (const float*)d_in[8];
  const float* bq     = (const float*)d_in[9];
  const float* bk     = (const float*)d_in[10];
  const float* bv     = (const float*)d_in[11];
  const float* bo     = (const float*)d_in[12];
  const float* b1     = (const float*)d_in[13];
  const float* b2     = (const float*)d_in[14];
  const float* ln1_g  = (const float*)d_in[15];
  const float* ln1_b  = (const float*)d_in[16];
  const float* ln2_g  = (const float*)d_in[17];
  const float* ln2_b  = (const float*)d_in[18];
  const float* enc_g  = (const float*)d_in[19];
  const float* enc_b  = (const float*)d_in[20];
  const float* fin_g  = (const float*)d_in[21];
  const float* fin_b  = (const float*)d_in[22];
  const float* Wout   = (const float*)d_in[23];
  const float* bout   = (const float*)d_in[24];
  float* out = (float*)d_out;

  uint8_t* p = (uint8_t*)d_ws;
  auto alloc = [&](size_t bytes) {
    void* r = (void*)p;
    p += (bytes + 255) & ~(size_t)255;
    return r;
  };
  float*          x     = (float*)alloc((size_t)MROWS * EDIM * 4);
  unsigned short* xb    = (unsigned short*)alloc((size_t)MROWS * EDIM * 2);
  float*          tbuf  = (float*)alloc((size_t)MROWS * EDIM * 4);
  unsigned short* qb    = (unsigned short*)alloc((size_t)MROWS * EDIM * 2);
  unsigned short* kb    = (unsigned short*)alloc((size_t)MROWS * EDIM * 2);
  unsigned short* vbuf  = (unsigned short*)alloc((size_t)MROWS * EDIM * 2);
  unsigned short* ctx   = (unsigned short*)alloc((size_t)MROWS * EDIM * 2);
  unsigned short* wlt   = (unsigned short*)alloc((size_t)NLAYER * 12 * 1024 * 1024 * 2);
  unsigned short* woutt = (unsigned short*)alloc((size_t)VOCAB * EDIM * 2);
  unsigned short* ff1   = qb;  // alias: qb..ctx (32MB) dead when ff1 is live
  if ((size_t)(p - (uint8_t*)d_ws) > ws_size) return;

  const dim3 blk(256);
  const size_t LW = (size_t)12 * 1024 * 1024;   // elems per layer in wlt
  const size_t M1 = 1024 * 1024;

  // weight transposes (f32 [K,N] -> bf16 [N,K])
  for (int i = 0; i < NLAYER; ++i) {
    unsigned short* lb = wlt + (size_t)i * LW;
    transpose_w<<<dim3(16, 16),  blk, 0, stream>>>(Wq + (size_t)i * M1, lb,          1024, 1024);
    transpose_w<<<dim3(16, 16),  blk, 0, stream>>>(Wk + (size_t)i * M1, lb + M1,     1024, 1024);
    transpose_w<<<dim3(16, 16),  blk, 0, stream>>>(Wv + (size_t)i * M1, lb + 2 * M1, 1024, 1024);
    transpose_w<<<dim3(16, 16),  blk, 0, stream>>>(Wo + (size_t)i * M1, lb + 3 * M1, 1024, 1024);
    transpose_w<<<dim3(16, 64),  blk, 0, stream>>>(W1 + (size_t)i * 4 * M1, lb + 4 * M1, 4096, 1024);
    transpose_w<<<dim3(64, 16),  blk, 0, stream>>>(W2 + (size_t)i * 4 * M1, lb + 8 * M1, 1024, 4096);
  }
  transpose_w<<<dim3(16, 500), blk, 0, stream>>>(Wout, woutt, VOCAB, 1024);

  embed_kernel<<<MROWS, blk, 0, stream>>>(tokens, emb, pe, x, xb);

  const int MB = MROWS / 128;
  for (int i = 0; i < NLAYER; ++i) {
    unsigned short* lb = wlt + (size_t)i * LW;
    gemm_bt<1, 0><<<MB * (EDIM / 128), blk, 0, stream>>>(xb, lb,          bq + i * EDIM, qb,   EDIM, EDIM, MB);
    gemm_bt<1, 0><<<MB * (EDIM / 128), blk, 0, stream>>>(xb, lb + M1,     bk + i * EDIM, kb,   EDIM, EDIM, MB);
    gemm_bt<1, 0><<<MB * (EDIM / 128), blk, 0, stream>>>(xb, lb + 2 * M1, bv + i * EDIM, vbuf, EDIM, EDIM, MB);
    attn_kernel<<<dim3(SEQ / 64, NHEAD, BATCH), blk, 0, stream>>>(qb, kb, vbuf, ctx);
    gemm_bt<0, 0><<<MB * (EDIM / 128), blk, 0, stream>>>(ctx, lb + 3 * M1, bo + i * EDIM, tbuf, EDIM, EDIM, MB);
    ln_add_kernel<<<MROWS, blk, 0, stream>>>(tbuf, ln1_g + i * EDIM, ln1_b + i * EDIM, x, xb);
    gemm_bt<1, 1><<<MB * (DFFDIM / 128), blk, 0, stream>>>(xb, lb + 4 * M1, b1 + i * DFFDIM, ff1, DFFDIM, EDIM, MB);
    gemm_bt<0, 0><<<MB * (EDIM / 128), blk, 0, stream>>>(ff1, lb + 8 * M1, b2 + i * EDIM, tbuf, EDIM, DFFDIM, MB);
    ln_add_kernel<<<MROWS, blk, 0, stream>>>(tbuf, ln2_g + i * EDIM, ln2_b + i * EDIM, x, xb);
  }

  final_ln_kernel<<<MROWS, blk, 0, stream>>>(x, enc_g, enc_b, fin_g, fin_b, xb);
  gemm_bt<0, 0><<<MB * (VOCAB / 128), blk, 0, stream>>>(xb, woutt, bout, out, VOCAB, EDIM, MB);
}

// Round 4
// 1895.005 us; speedup vs baseline: 1.6484x; 1.2823x over previous
//
#include <hip/hip_runtime.h>
#include <hip/hip_bf16.h>
#include <stdint.h>

#define EDIM 1024
#define DFFDIM 4096
#define NLAYER 4
#define BATCH 4
#define SEQ 1024
#define NHEAD 16
#define DHEAD 64
#define VOCAB 32000
#define MROWS (BATCH*SEQ)
#define QKVLD (3*EDIM)
#define EPSF 1e-6f

typedef float f32x4 __attribute__((ext_vector_type(4)));
typedef short s16x8 __attribute__((ext_vector_type(8)));
typedef __bf16 bf16x8 __attribute__((ext_vector_type(8)));

__device__ inline unsigned short f2bf(float f) {
  union { float f; uint32_t u; } v; v.f = f;
  uint32_t r = v.u + 0x7fffu + ((v.u >> 16) & 1u);
  return (unsigned short)(r >> 16);
}

__device__ __forceinline__ void gload16(const void* g, void* l) {
  __builtin_amdgcn_global_load_lds(
      (const __attribute__((address_space(1))) void*)g,
      (__attribute__((address_space(3))) void*)l, 16, 0, 0);
}

// ---------------- embedding + positional encoding ----------------
__global__ __launch_bounds__(256) void embed_kernel(
    const int* __restrict__ tokens, const float* __restrict__ emb,
    const float* __restrict__ pe, float* __restrict__ x,
    unsigned short* __restrict__ xb) {
  const int row = blockIdx.x;
  const int s = row & (SEQ - 1);
  const int tok = tokens[row];
  const int c = threadIdx.x * 4;
  float4 ev = *(const float4*)(emb + (size_t)tok * EDIM + c);
  float4 pv = *(const float4*)(pe + (size_t)s * EDIM + c);
  float4 o;
  o.x = ev.x + pv.x; o.y = ev.y + pv.y; o.z = ev.z + pv.z; o.w = ev.w + pv.w;
  *(float4*)(x + (size_t)row * EDIM + c) = o;
  unsigned short* xr = xb + (size_t)row * EDIM + c;
  xr[0] = f2bf(o.x); xr[1] = f2bf(o.y); xr[2] = f2bf(o.z); xr[3] = f2bf(o.w);
}

// ---------------- weight transpose+convert: src f32 [K,N] -> dst bf16 [N,K] ----------------
__global__ __launch_bounds__(256) void transpose_w(
    const float* __restrict__ src, unsigned short* __restrict__ dst,
    int N, int K) {
  __shared__ float tl[64][65];
  const int t = threadIdx.x;
  const int k0 = blockIdx.x * 64, n0 = blockIdx.y * 64;
  const int c = (t & 15) * 4, r0 = t >> 4;
  #pragma unroll
  for (int i = 0; i < 4; ++i) {
    const int r = r0 + i * 16;
    float4 v = *(const float4*)(src + (size_t)(k0 + r) * N + n0 + c);
    tl[r][c] = v.x; tl[r][c + 1] = v.y; tl[r][c + 2] = v.z; tl[r][c + 3] = v.w;
  }
  __syncthreads();
  #pragma unroll
  for (int i = 0; i < 4; ++i) {
    const int n = r0 + i * 16;
    uint2 o;
    o.x = (uint32_t)f2bf(tl[c + 0][n]) | ((uint32_t)f2bf(tl[c + 1][n]) << 16);
    o.y = (uint32_t)f2bf(tl[c + 2][n]) | ((uint32_t)f2bf(tl[c + 3][n]) << 16);
    *(uint2*)(dst + (size_t)(n0 + n) * K + k0 + c) = o;
  }
}

// ---------------- pack qkv bias: [bq_i | bk_i | bv_i] per layer ----------------
__global__ __launch_bounds__(256) void pack_bias(
    const float* __restrict__ bq, const float* __restrict__ bk,
    const float* __restrict__ bv, float* __restrict__ dst) {
  const int idx = blockIdx.x * 256 + threadIdx.x;
  if (idx >= NLAYER * QKVLD) return;
  const int layer = idx / QKVLD, c = idx % QKVLD;
  float v;
  if (c < 1024)      v = bq[layer * 1024 + c];
  else if (c < 2048) v = bk[layer * 1024 + c - 1024];
  else               v = bv[layer * 1024 + c - 2048];
  dst[idx] = v;
}

// ---------------- 2-phase dbuf GEMM: C[M,N] = A_bf16[M,K] @ Bt_bf16[N,K] + bias ----------------
// 128x128 tile, BK=32, 4 waves (2x2), global_load_lds width=16, double-buffered LDS.
template<int OUT_BF16, int RELU>
__global__ __launch_bounds__(256) void gemm_bt(
    const unsigned short* __restrict__ A, const unsigned short* __restrict__ Bt,
    const float* __restrict__ bias, void* __restrict__ Cout,
    int Nld, int K, int MBLK) {
  __shared__ unsigned short sm[2][8192];   // [buf][ A 4096 elems | B 4096 elems ]
  const int t = threadIdx.x, lane = t & 63;
  const int wave = t >> 6, wr = wave >> 1, wc = wave & 1;
  const int l15 = lane & 15, lg = lane >> 4;

  // bijective XCD swizzle (gridDim.x % 8 == 0 for all our shapes)
  const int cpx = gridDim.x >> 3;
  const int bid = blockIdx.x;
  const int swz = (bid & 7) * cpx + (bid >> 3);
  const int m0 = (swz % MBLK) * 128;
  const int n0 = (swz / MBLK) * 128;

  f32x4 acc[4][4];
  #pragma unroll
  for (int i = 0; i < 4; ++i)
    #pragma unroll
    for (int j = 0; j < 4; ++j)
      acc[i][j] = (f32x4){0.f, 0.f, 0.f, 0.f};

  // staging map: wave w covers rows w*32..w*32+31 (two 16-row chunks); LDS = base + lane*16B
  const int srow = wave * 32 + (lane >> 2);
  const int scol = (lane & 3) * 8;
  const unsigned short* agp = A + (size_t)(m0 + srow) * K + scol;
  const unsigned short* bgp = Bt + (size_t)(n0 + srow) * K + scol;
  const size_t rstep = (size_t)16 * K;
  const int loff = wave * 1024 + lane * 8;

  auto stage = [&](int buf, int k0) {
    unsigned short* l = &sm[buf][loff];
    gload16(agp + k0, l);
    gload16(agp + rstep + k0, l + 512);
    gload16(bgp + k0, l + 4096);
    gload16(bgp + rstep + k0, l + 4096 + 512);
  };

  stage(0, 0);
  __syncthreads();
  int cur = 0;
  for (int k0 = 0; k0 < K; k0 += 32) {
    if (k0 + 32 < K) stage(cur ^ 1, k0 + 32);   // prefetch next tile (overlaps MFMA)

    bf16x8 af[4], bfr[4];
    #pragma unroll
    for (int mf = 0; mf < 4; ++mf)
      af[mf] = *(const bf16x8*)&sm[cur][(wr * 64 + mf * 16 + l15) * 32 + lg * 8];
    #pragma unroll
    for (int nf = 0; nf < 4; ++nf)
      bfr[nf] = *(const bf16x8*)&sm[cur][4096 + (wc * 64 + nf * 16 + l15) * 32 + lg * 8];
    #pragma unroll
    for (int mf = 0; mf < 4; ++mf)
      #pragma unroll
      for (int nf = 0; nf < 4; ++nf)
        acc[mf][nf] = __builtin_amdgcn_mfma_f32_16x16x32_bf16(af[mf], bfr[nf], acc[mf][nf], 0, 0, 0);

    __syncthreads();   // drains prefetch vmcnt + guards dbuf swap
    cur ^= 1;
  }

  #pragma unroll
  for (int mf = 0; mf < 4; ++mf) {
    #pragma unroll
    for (int nf = 0; nf < 4; ++nf) {
      const int col = n0 + wc * 64 + nf * 16 + l15;
      const float bv = bias[col];
      #pragma unroll
      for (int r = 0; r < 4; ++r) {
        const int row = m0 + wr * 64 + mf * 16 + lg * 4 + r;
        float val = acc[mf][nf][r] + bv;
        if (RELU) val = fmaxf(val, 0.f);
        if (OUT_BF16)
          ((unsigned short*)Cout)[(size_t)row * Nld + col] = f2bf(val);
        else
          ((float*)Cout)[(size_t)row * Nld + col] = val;
      }
    }
  }
}

// ---------------- flash attention on fused qkv buffer [M][3072] ----------------
__global__ __launch_bounds__(256) void attn_kernel(
    const unsigned short* __restrict__ qkv, unsigned short* __restrict__ ctx) {
  const int b = blockIdx.z, h = blockIdx.y;
  const int t = threadIdx.x, wave = t >> 6, lane = t & 63;
  const int l15 = lane & 15, lg = lane >> 4;
  const int qrow0 = blockIdx.x * 64 + wave * 16;
  const unsigned short* qbs = qkv + (size_t)b * SEQ * QKVLD + h * DHEAD;
  const unsigned short* kbs = qbs + EDIM;
  const unsigned short* vbs = qbs + 2 * EDIM;
  __shared__ unsigned short Ksm[32][72];     // 32 kv x 64 d (+8 pad)
  __shared__ unsigned short VTs[64 * 32];    // linear, XOR-swizzled: byte ^= ((d>>3)&7)<<4
  __shared__ unsigned short p_lds[4][16][40];

  const unsigned short* qp = qbs + (size_t)(qrow0 + l15) * QKVLD + lg * 8;
  bf16x8 a0 = *(const bf16x8*)qp;
  bf16x8 a1 = *(const bf16x8*)(qp + 32);

  f32x4 o0 = {0,0,0,0}, o1 = {0,0,0,0}, o2 = {0,0,0,0}, o3 = {0,0,0,0};
  float m[4], ls[4];
  #pragma unroll
  for (int r = 0; r < 4; ++r) { m[r] = -1e30f; ls[r] = 0.f; }

  const int sr = t >> 3;            // kv row 0..31
  const int sc = (t & 7) * 8;       // d col 0..56
  const unsigned short* kgp = kbs + (size_t)sr * QKVLD + sc;
  const unsigned short* vgp = vbs + (size_t)sr * QKVLD + sc;
  const size_t tilestep = (size_t)32 * QKVLD;

  s16x8 kreg = *(const s16x8*)kgp;         // T14: tile 0 pre-loaded to regs
  s16x8 vreg = *(const s16x8*)vgp;
  const int xw = (sc >> 3) << 4;           // write-side swizzle term (thread-const)

  const int NT = SEQ / 32;
  for (int j = 0; j < NT; ++j) {
    // write staged regs to LDS
    *(s16x8*)&Ksm[sr][sc] = kreg;
    #pragma unroll
    for (int e = 0; e < 8; ++e) {
      const int byteo = (((sc + e) * 32 + sr) * 2) ^ xw;
      *(unsigned short*)((char*)VTs + byteo) = (unsigned short)vreg[e];
    }
    __syncthreads();

    bf16x8 b00 = *(const bf16x8*)&Ksm[l15][lg * 8];
    bf16x8 b01 = *(const bf16x8*)&Ksm[l15][32 + lg * 8];
    bf16x8 b10 = *(const bf16x8*)&Ksm[16 + l15][lg * 8];
    bf16x8 b11 = *(const bf16x8*)&Ksm[16 + l15][32 + lg * 8];
    f32x4 s0 = {0,0,0,0}, s1 = {0,0,0,0};
    __builtin_amdgcn_s_setprio(1);
    s0 = __builtin_amdgcn_mfma_f32_16x16x32_bf16(a0, b00, s0, 0, 0, 0);
    s0 = __builtin_amdgcn_mfma_f32_16x16x32_bf16(a1, b01, s0, 0, 0, 0);
    s1 = __builtin_amdgcn_mfma_f32_16x16x32_bf16(a0, b10, s1, 0, 0, 0);
    s1 = __builtin_amdgcn_mfma_f32_16x16x32_bf16(a1, b11, s1, 0, 0, 0);
    __builtin_amdgcn_s_setprio(0);

    // T14: issue next tile's global loads; latency hides under softmax+PV
    if (j + 1 < NT) {
      kreg = *(const s16x8*)(kgp + (size_t)(j + 1) * tilestep);
      vreg = *(const s16x8*)(vgp + (size_t)(j + 1) * tilestep);
    }

    float mx[4], p0[4], p1[4], scl[4], rs[4];
    #pragma unroll
    for (int r = 0; r < 4; ++r) { s0[r] *= 0.125f; s1[r] *= 0.125f; mx[r] = fmaxf(s0[r], s1[r]); }
    #pragma unroll
    for (int off = 1; off < 16; off <<= 1) {
      #pragma unroll
      for (int r = 0; r < 4; ++r) mx[r] = fmaxf(mx[r], __shfl_xor(mx[r], off));
    }
    #pragma unroll
    for (int r = 0; r < 4; ++r) {
      const float mn = fmaxf(m[r], mx[r]);
      scl[r] = __expf(m[r] - mn);
      m[r] = mn;
      p0[r] = __expf(s0[r] - mn);
      p1[r] = __expf(s1[r] - mn);
      rs[r] = p0[r] + p1[r];
    }
    #pragma unroll
    for (int off = 1; off < 16; off <<= 1) {
      #pragma unroll
      for (int r = 0; r < 4; ++r) rs[r] += __shfl_xor(rs[r], off);
    }
    #pragma unroll
    for (int r = 0; r < 4; ++r) {
      ls[r] = ls[r] * scl[r] + rs[r];
      o0[r] *= scl[r]; o1[r] *= scl[r]; o2[r] *= scl[r]; o3[r] *= scl[r];
      p_lds[wave][lg * 4 + r][l15]      = f2bf(p0[r]);
      p_lds[wave][lg * 4 + r][16 + l15] = f2bf(p1[r]);
    }
    bf16x8 pa = *(const bf16x8*)&p_lds[wave][l15][lg * 8];

    auto vld = [&](int d0) {
      const int d = d0 + l15;
      const int byteo = ((d * 32 + lg * 8) * 2) ^ (((d >> 3) & 7) << 4);
      return *(const bf16x8*)((const char*)VTs + byteo);
    };
    bf16x8 v0 = vld(0), v1 = vld(16), v2 = vld(32), v3 = vld(48);
    __builtin_amdgcn_s_setprio(1);
    o0 = __builtin_amdgcn_mfma_f32_16x16x32_bf16(pa, v0, o0, 0, 0, 0);
    o1 = __builtin_amdgcn_mfma_f32_16x16x32_bf16(pa, v1, o1, 0, 0, 0);
    o2 = __builtin_amdgcn_mfma_f32_16x16x32_bf16(pa, v2, o2, 0, 0, 0);
    o3 = __builtin_amdgcn_mfma_f32_16x16x32_bf16(pa, v3, o3, 0, 0, 0);
    __builtin_amdgcn_s_setprio(0);
    __syncthreads();
  }

  unsigned short* cp = ctx + (size_t)b * SEQ * EDIM + h * DHEAD;
  #pragma unroll
  for (int r = 0; r < 4; ++r) {
    unsigned short* cr = cp + (size_t)(qrow0 + lg * 4 + r) * EDIM;
    const float inv = 1.f / ls[r];
    cr[l15]      = f2bf(o0[r] * inv);
    cr[16 + l15] = f2bf(o1[r] * inv);
    cr[32 + l15] = f2bf(o2[r] * inv);
    cr[48 + l15] = f2bf(o3[r] * inv);
  }
}

// ---------------- residual + layernorm ----------------
__global__ __launch_bounds__(256) void ln_add_kernel(
    const float* __restrict__ a, const float* __restrict__ g, const float* __restrict__ bb,
    float* __restrict__ x, unsigned short* __restrict__ xb) {
  const int row = blockIdx.x, t = threadIdx.x;
  const float* ar = a + (size_t)row * EDIM;
  float4 av = *(const float4*)(ar + t * 4);
  float s = av.x + av.y + av.z + av.w;
  float qq = av.x * av.x + av.y * av.y + av.z * av.z + av.w * av.w;
  #pragma unroll
  for (int off = 1; off < 64; off <<= 1) { s += __shfl_xor(s, off); qq += __shfl_xor(qq, off); }
  __shared__ float red[8];
  const int wv = t >> 6;
  if ((t & 63) == 0) { red[wv] = s; red[4 + wv] = qq; }
  __syncthreads();
  s = red[0] + red[1] + red[2] + red[3];
  qq = red[4] + red[5] + red[6] + red[7];
  const float mean = s * (1.f / EDIM);
  const float rstd = rsqrtf(qq * (1.f / EDIM) - mean * mean + EPSF);
  float4 gv = *(const float4*)(g + t * 4);
  float4 bv = *(const float4*)(bb + t * 4);
  float* xr = x + (size_t)row * EDIM;
  float4 xv = *(float4*)(xr + t * 4);
  float4 o;
  o.x = xv.x + (av.x - mean) * rstd * gv.x + bv.x;
  o.y = xv.y + (av.y - mean) * rstd * gv.y + bv.y;
  o.z = xv.z + (av.z - mean) * rstd * gv.z + bv.z;
  o.w = xv.w + (av.w - mean) * rstd * gv.w + bv.w;
  *(float4*)(xr + t * 4) = o;
  unsigned short* xbr = xb + (size_t)row * EDIM + t * 4;
  xbr[0] = f2bf(o.x); xbr[1] = f2bf(o.y); xbr[2] = f2bf(o.z); xbr[3] = f2bf(o.w);
}

// ---------------- final double layernorm -> bf16 ----------------
__global__ __launch_bounds__(256) void final_ln_kernel(
    const float* __restrict__ x, const float* __restrict__ g1, const float* __restrict__ b1,
    const float* __restrict__ g2, const float* __restrict__ b2,
    unsigned short* __restrict__ xb) {
  const int row = blockIdx.x, t = threadIdx.x;
  __shared__ float red[8];
  const int wv = t >> 6;
  const float* xr = x + (size_t)row * EDIM;
  float4 v = *(const float4*)(xr + t * 4);

  float s = v.x + v.y + v.z + v.w;
  float qq = v.x * v.x + v.y * v.y + v.z * v.z + v.w * v.w;
  #pragma unroll
  for (int off = 1; off < 64; off <<= 1) { s += __shfl_xor(s, off); qq += __shfl_xor(qq, off); }
  if ((t & 63) == 0) { red[wv] = s; red[4 + wv] = qq; }
  __syncthreads();
  s = red[0] + red[1] + red[2] + red[3];
  qq = red[4] + red[5] + red[6] + red[7];
  __syncthreads();
  float mean = s * (1.f / EDIM);
  float rstd = rsqrtf(qq * (1.f / EDIM) - mean * mean + EPSF);
  float4 g1v = *(const float4*)(g1 + t * 4);
  float4 b1v = *(const float4*)(b1 + t * 4);
  float4 tv;
  tv.x = (v.x - mean) * rstd * g1v.x + b1v.x;
  tv.y = (v.y - mean) * rstd * g1v.y + b1v.y;
  tv.z = (v.z - mean) * rstd * g1v.z + b1v.z;
  tv.w = (v.w - mean) * rstd * g1v.w + b1v.w;

  s = tv.x + tv.y + tv.z + tv.w;
  qq = tv.x * tv.x + tv.y * tv.y + tv.z * tv.z + tv.w * tv.w;
  #pragma unroll
  for (int off = 1; off < 64; off <<= 1) { s += __shfl_xor(s, off); qq += __shfl_xor(qq, off); }
  if ((t & 63) == 0) { red[wv] = s; red[4 + wv] = qq; }
  __syncthreads();
  s = red[0] + red[1] + red[2] + red[3];
  qq = red[4] + red[5] + red[6] + red[7];
  mean = s * (1.f / EDIM);
  rstd = rsqrtf(qq * (1.f / EDIM) - mean * mean + EPSF);
  float4 g2v = *(const float4*)(g2 + t * 4);
  float4 b2v = *(const float4*)(b2 + t * 4);
  unsigned short* o = xb + (size_t)row * EDIM + t * 4;
  o[0] = f2bf((tv.x - mean) * rstd * g2v.x + b2v.x);
  o[1] = f2bf((tv.y - mean) * rstd * g2v.y + b2v.y);
  o[2] = f2bf((tv.z - mean) * rstd * g2v.z + b2v.z);
  o[3] = f2bf((tv.w - mean) * rstd * g2v.w + b2v.w);
}

// ---------------- launch ----------------
extern "C" void kernel_launch(void* const* d_in, const int* in_sizes, int n_in,
                              void* d_out, int out_size, void* d_ws, size_t ws_size,
                              hipStream_t stream) {
  const int*   tokens = (const int*)d_in[0];
  const float* emb    = (const float*)d_in[1];
  const float* pe     = (const float*)d_in[2];
  const float* Wq     = (const float*)d_in[3];
  const float* Wk     = (const float*)d_in[4];
  const float* Wv     = (const float*)d_in[5];
  const float* Wo     = (const float*)d_in[6];
  const float* W1     = (const float*)d_in[7];
  const float* W2     = (const float*)d_in[8];
  const float* bq     = (const float*)d_in[9];
  const float* bk     = (const float*)d_in[10];
  const float* bv     = (const float*)d_in[11];
  const float* bo     = (const float*)d_in[12];
  const float* b1     = (const float*)d_in[13];
  const float* b2     = (const float*)d_in[14];
  const float* ln1_g  = (const float*)d_in[15];
  const float* ln1_b  = (const float*)d_in[16];
  const float* ln2_g  = (const float*)d_in[17];
  const float* ln2_b  = (const float*)d_in[18];
  const float* enc_g  = (const float*)d_in[19];
  const float* enc_b  = (const float*)d_in[20];
  const float* fin_g  = (const float*)d_in[21];
  const float* fin_b  = (const float*)d_in[22];
  const float* Wout   = (const float*)d_in[23];
  const float* bout   = (const float*)d_in[24];
  float* out = (float*)d_out;

  uint8_t* p = (uint8_t*)d_ws;
  auto alloc = [&](size_t bytes) {
    void* r = (void*)p;
    p += (bytes + 255) & ~(size_t)255;
    return r;
  };
  float*          x     = (float*)alloc((size_t)MROWS * EDIM * 4);
  unsigned short* xb    = (unsigned short*)alloc((size_t)MROWS * EDIM * 2);
  float*          tbuf  = (float*)alloc((size_t)MROWS * EDIM * 4);
  unsigned short* qkv   = (unsigned short*)alloc((size_t)MROWS * QKVLD * 2);  // 24 MB
  unsigned short* ctx   = (unsigned short*)alloc((size_t)MROWS * EDIM * 2);   // 8 MB, right after qkv
  unsigned short* wlt   = (unsigned short*)alloc((size_t)NLAYER * 12 * 1024 * 1024 * 2);
  unsigned short* woutt = (unsigned short*)alloc((size_t)VOCAB * EDIM * 2);
  float*          bqkv  = (float*)alloc((size_t)NLAYER * QKVLD * 4);
  unsigned short* ff1   = qkv;  // alias: qkv(24MB)+ctx(8MB) dead when ff1 (32MB) is live
  if ((size_t)(p - (uint8_t*)d_ws) > ws_size) return;

  const dim3 blk(256);
  const size_t LW = (size_t)12 * 1024 * 1024;   // elems per layer in wlt
  const size_t M1 = 1024 * 1024;

  // weight transposes (f32 [K,N] -> bf16 [N,K]); WqT|WkT|WvT contiguous = fused [3072][1024]
  for (int i = 0; i < NLAYER; ++i) {
    unsigned short* lb = wlt + (size_t)i * LW;
    transpose_w<<<dim3(16, 16),  blk, 0, stream>>>(Wq + (size_t)i * M1, lb,          1024, 1024);
    transpose_w<<<dim3(16, 16),  blk, 0, stream>>>(Wk + (size_t)i * M1, lb + M1,     1024, 1024);
    transpose_w<<<dim3(16, 16),  blk, 0, stream>>>(Wv + (size_t)i * M1, lb + 2 * M1, 1024, 1024);
    transpose_w<<<dim3(16, 16),  blk, 0, stream>>>(Wo + (size_t)i * M1, lb + 3 * M1, 1024, 1024);
    transpose_w<<<dim3(16, 64),  blk, 0, stream>>>(W1 + (size_t)i * 4 * M1, lb + 4 * M1, 4096, 1024);
    transpose_w<<<dim3(64, 16),  blk, 0, stream>>>(W2 + (size_t)i * 4 * M1, lb + 8 * M1, 1024, 4096);
  }
  transpose_w<<<dim3(16, 500), blk, 0, stream>>>(Wout, woutt, VOCAB, 1024);
  pack_bias<<<(NLAYER * QKVLD + 255) / 256, blk, 0, stream>>>(bq, bk, bv, bqkv);

  embed_kernel<<<MROWS, blk, 0, stream>>>(tokens, emb, pe, x, xb);

  const int MB = MROWS / 128;
  for (int i = 0; i < NLAYER; ++i) {
    unsigned short* lb = wlt + (size_t)i * LW;
    // fused QKV: [M,1024] @ [1024,3072]
    gemm_bt<1, 0><<<MB * (QKVLD / 128), blk, 0, stream>>>(
        xb, lb, bqkv + (size_t)i * QKVLD, qkv, QKVLD, EDIM, MB);
    attn_kernel<<<dim3(SEQ / 64, NHEAD, BATCH), blk, 0, stream>>>(qkv, ctx);
    gemm_bt<0, 0><<<MB * (EDIM / 128), blk, 0, stream>>>(ctx, lb + 3 * M1, bo + i * EDIM, tbuf, EDIM, EDIM, MB);
    ln_add_kernel<<<MROWS, blk, 0, stream>>>(tbuf, ln1_g + i * EDIM, ln1_b + i * EDIM, x, xb);
    gemm_bt<1, 1><<<MB * (DFFDIM / 128), blk, 0, stream>>>(xb, lb + 4 * M1, b1 + i * DFFDIM, ff1, DFFDIM, EDIM, MB);
    gemm_bt<0, 0><<<MB * (EDIM / 128), blk, 0, stream>>>(ff1, lb + 8 * M1, b2 + i * EDIM, tbuf, EDIM, DFFDIM, MB);
    ln_add_kernel<<<MROWS, blk, 0, stream>>>(tbuf, ln2_g + i * EDIM, ln2_b + i * EDIM, x, xb);
  }

  final_ln_kernel<<<MROWS, blk, 0, stream>>>(x, enc_g, enc_b, fin_g, fin_b, xb);
  gemm_bt<0, 0><<<MB * (VOCAB / 128), blk, 0, stream>>>(xb, woutt, bout, out, VOCAB, EDIM, MB);
}

// Round 5
// 1766.175 us; speedup vs baseline: 1.7686x; 1.0729x over previous
//
#include <hip/hip_runtime.h>
#include <hip/hip_bf16.h>
#include <stdint.h>

#define EDIM 1024
#define DFFDIM 4096
#define NLAYER 4
#define BATCH 4
#define SEQ 1024
#define NHEAD 16
#define DHEAD 64
#define VOCAB 32000
#define MROWS (BATCH*SEQ)
#define QKVLD (3*EDIM)
#define EPSF 1e-6f

typedef float f32x4 __attribute__((ext_vector_type(4)));
typedef short s16x8 __attribute__((ext_vector_type(8)));
typedef __bf16 bf16x8 __attribute__((ext_vector_type(8)));

__device__ inline unsigned short f2bf(float f) {
  union { float f; uint32_t u; } v; v.f = f;
  uint32_t r = v.u + 0x7fffu + ((v.u >> 16) & 1u);
  return (unsigned short)(r >> 16);
}

__device__ __forceinline__ void gload16(const void* g, void* l) {
  __builtin_amdgcn_global_load_lds(
      (const __attribute__((address_space(1))) void*)g,
      (__attribute__((address_space(3))) void*)l, 16, 0, 0);
}

// ---------------- embedding + positional encoding ----------------
__global__ __launch_bounds__(256) void embed_kernel(
    const int* __restrict__ tokens, const float* __restrict__ emb,
    const float* __restrict__ pe, float* __restrict__ x,
    unsigned short* __restrict__ xb) {
  const int row = blockIdx.x;
  const int s = row & (SEQ - 1);
  const int tok = tokens[row];
  const int c = threadIdx.x * 4;
  float4 ev = *(const float4*)(emb + (size_t)tok * EDIM + c);
  float4 pv = *(const float4*)(pe + (size_t)s * EDIM + c);
  float4 o;
  o.x = ev.x + pv.x; o.y = ev.y + pv.y; o.z = ev.z + pv.z; o.w = ev.w + pv.w;
  *(float4*)(x + (size_t)row * EDIM + c) = o;
  unsigned short* xr = xb + (size_t)row * EDIM + c;
  xr[0] = f2bf(o.x); xr[1] = f2bf(o.y); xr[2] = f2bf(o.z); xr[3] = f2bf(o.w);
}

// ---------------- weight transpose+convert: src f32 [K,N] -> dst bf16 [N,K] ----------------
__global__ __launch_bounds__(256) void transpose_w(
    const float* __restrict__ src, unsigned short* __restrict__ dst,
    int N, int K) {
  __shared__ float tl[64][65];
  const int t = threadIdx.x;
  const int k0 = blockIdx.x * 64, n0 = blockIdx.y * 64;
  const int c = (t & 15) * 4, r0 = t >> 4;
  #pragma unroll
  for (int i = 0; i < 4; ++i) {
    const int r = r0 + i * 16;
    float4 v = *(const float4*)(src + (size_t)(k0 + r) * N + n0 + c);
    tl[r][c] = v.x; tl[r][c + 1] = v.y; tl[r][c + 2] = v.z; tl[r][c + 3] = v.w;
  }
  __syncthreads();
  #pragma unroll
  for (int i = 0; i < 4; ++i) {
    const int n = r0 + i * 16;
    uint2 o;
    o.x = (uint32_t)f2bf(tl[c + 0][n]) | ((uint32_t)f2bf(tl[c + 1][n]) << 16);
    o.y = (uint32_t)f2bf(tl[c + 2][n]) | ((uint32_t)f2bf(tl[c + 3][n]) << 16);
    *(uint2*)(dst + (size_t)(n0 + n) * K + k0 + c) = o;
  }
}

// ---------------- pack qkv bias ----------------
__global__ __launch_bounds__(256) void pack_bias(
    const float* __restrict__ bq, const float* __restrict__ bk,
    const float* __restrict__ bv, float* __restrict__ dst) {
  const int idx = blockIdx.x * 256 + threadIdx.x;
  if (idx >= NLAYER * QKVLD) return;
  const int layer = idx / QKVLD, c = idx % QKVLD;
  float v;
  if (c < 1024)      v = bq[layer * 1024 + c];
  else if (c < 2048) v = bk[layer * 1024 + c - 1024];
  else               v = bv[layer * 1024 + c - 2048];
  dst[idx] = v;
}

// ---------------- 256x256 deep-pipelined GEMM (T2+T3+T4+T5) ----------------
// BK=32, 8 waves (2Mx4N), 64KB LDS dbuf, counted vmcnt, swizzled LDS.
// LDS elem (r,c) at byte r*64 + ((c*2) ^ (((r>>1)&3)<<4)); conflict-free b128 reads.
template<int OUT_BF16, int RELU>
__global__ __launch_bounds__(512, 2) void gemm256(
    const unsigned short* __restrict__ A, const unsigned short* __restrict__ Bt,
    const float* __restrict__ bias, void* __restrict__ Cout,
    int Nld, int K, int MBLK) {
  __shared__ __attribute__((aligned(16))) unsigned short sm[32768];  // 2 bufs x (A 16KB | B 16KB)
  const int t = threadIdx.x, lane = t & 63;
  const int wave = t >> 6, wr = wave >> 2, wc = wave & 3;
  const int l15 = lane & 15, lg = lane >> 4;

  const int cpx = gridDim.x >> 3;               // grid % 8 == 0 for all shapes
  const int bid = blockIdx.x;
  const int swzb = (bid & 7) * cpx + (bid >> 3);
  const int m0 = (swzb % MBLK) * 256;
  const int n0 = (swzb / MBLK) * 256;

  f32x4 acc[8][4];
  #pragma unroll
  for (int i = 0; i < 8; ++i)
    #pragma unroll
    for (int j = 0; j < 4; ++j)
      acc[i][j] = (f32x4){0.f, 0.f, 0.f, 0.f};

  // staging: thread t covers rows sr_, sr_+128 for A and B; source col pre-swizzled
  const int sr_ = t >> 2;
  const int scs = ((t & 3) * 8) ^ (((sr_ >> 1) & 3) << 3);
  const unsigned short* agp = A  + (size_t)(m0 + sr_) * K + scs;
  const unsigned short* bgp = Bt + (size_t)(n0 + sr_) * K + scs;
  const size_t rstep128 = (size_t)128 * K;
  char* smb = (char*)sm;
  char* dst0 = smb + t * 16;

  // read-side swizzled base offsets (bytes); + mf*1024 / + nf*1024 per fragment
  const int colx = (lg * 16) ^ (((l15 >> 1) & 3) << 4);
  const int rdA = (wr * 128 + l15) * 64 + colx;
  const int rdB = 16384 + (wc * 64 + l15) * 64 + colx;

  // prologue: stage tile 0 into buf 0
  {
    char* d = dst0;
    gload16(agp, d);
    gload16(agp + rstep128, d + 8192);
    gload16(bgp, d + 16384);
    gload16(bgp + rstep128, d + 24576);
  }

  const int NT = K / 32;
  for (int tt = 0; tt < NT; ++tt) {
    const int cur = tt & 1;
    if (tt + 1 < NT) {
      const int k0 = (tt + 1) * 32;
      char* d = dst0 + (cur ^ 1) * 32768;
      gload16(agp + k0, d);
      gload16(agp + rstep128 + k0, d + 8192);
      gload16(bgp + k0, d + 16384);
      gload16(bgp + rstep128 + k0, d + 24576);
      asm volatile("s_waitcnt vmcnt(4)" ::: "memory");   // tile tt done; 4 prefetch stay in flight
    } else {
      asm volatile("s_waitcnt vmcnt(0)" ::: "memory");
    }
    __builtin_amdgcn_sched_barrier(0);
    __builtin_amdgcn_s_barrier();
    __builtin_amdgcn_sched_barrier(0);

    const char* ab = smb + cur * 32768;
    bf16x8 af[8], bf[4];
    #pragma unroll
    for (int mf = 0; mf < 8; ++mf)
      af[mf] = *(const bf16x8*)(ab + rdA + mf * 1024);
    #pragma unroll
    for (int nf = 0; nf < 4; ++nf)
      bf[nf] = *(const bf16x8*)(ab + rdB + nf * 1024);

    __builtin_amdgcn_s_setprio(1);
    #pragma unroll
    for (int mf = 0; mf < 8; ++mf)
      #pragma unroll
      for (int nf = 0; nf < 4; ++nf)
        acc[mf][nf] = __builtin_amdgcn_mfma_f32_16x16x32_bf16(af[mf], bf[nf], acc[mf][nf], 0, 0, 0);
    __builtin_amdgcn_s_setprio(0);

    __builtin_amdgcn_sched_barrier(0);
    __builtin_amdgcn_s_barrier();
  }

  #pragma unroll
  for (int mf = 0; mf < 8; ++mf) {
    #pragma unroll
    for (int nf = 0; nf < 4; ++nf) {
      const int col = n0 + wc * 64 + nf * 16 + l15;
      const float bv = bias[col];
      #pragma unroll
      for (int r = 0; r < 4; ++r) {
        const int row = m0 + wr * 128 + mf * 16 + lg * 4 + r;
        float val = acc[mf][nf][r] + bv;
        if (RELU) val = fmaxf(val, 0.f);
        if (OUT_BF16)
          ((unsigned short*)Cout)[(size_t)row * Nld + col] = f2bf(val);
        else
          ((float*)Cout)[(size_t)row * Nld + col] = val;
      }
    }
  }
}

// ---------------- 128x128 2-phase dbuf GEMM (for N=1024 shapes) ----------------
template<int OUT_BF16, int RELU>
__global__ __launch_bounds__(256) void gemm_bt(
    const unsigned short* __restrict__ A, const unsigned short* __restrict__ Bt,
    const float* __restrict__ bias, void* __restrict__ Cout,
    int Nld, int K, int MBLK) {
  __shared__ unsigned short sm[2][8192];
  const int t = threadIdx.x, lane = t & 63;
  const int wave = t >> 6, wr = wave >> 1, wc = wave & 1;
  const int l15 = lane & 15, lg = lane >> 4;

  const int cpx = gridDim.x >> 3;
  const int bid = blockIdx.x;
  const int swz = (bid & 7) * cpx + (bid >> 3);
  const int m0 = (swz % MBLK) * 128;
  const int n0 = (swz / MBLK) * 128;

  f32x4 acc[4][4];
  #pragma unroll
  for (int i = 0; i < 4; ++i)
    #pragma unroll
    for (int j = 0; j < 4; ++j)
      acc[i][j] = (f32x4){0.f, 0.f, 0.f, 0.f};

  const int srow = wave * 32 + (lane >> 2);
  const int scol = (lane & 3) * 8;
  const unsigned short* agp = A + (size_t)(m0 + srow) * K + scol;
  const unsigned short* bgp = Bt + (size_t)(n0 + srow) * K + scol;
  const size_t rstep = (size_t)16 * K;
  const int loff = wave * 1024 + lane * 8;

  auto stage = [&](int buf, int k0) {
    unsigned short* l = &sm[buf][loff];
    gload16(agp + k0, l);
    gload16(agp + rstep + k0, l + 512);
    gload16(bgp + k0, l + 4096);
    gload16(bgp + rstep + k0, l + 4096 + 512);
  };

  stage(0, 0);
  __syncthreads();
  int cur = 0;
  for (int k0 = 0; k0 < K; k0 += 32) {
    if (k0 + 32 < K) stage(cur ^ 1, k0 + 32);

    bf16x8 af[4], bfr[4];
    #pragma unroll
    for (int mf = 0; mf < 4; ++mf)
      af[mf] = *(const bf16x8*)&sm[cur][(wr * 64 + mf * 16 + l15) * 32 + lg * 8];
    #pragma unroll
    for (int nf = 0; nf < 4; ++nf)
      bfr[nf] = *(const bf16x8*)&sm[cur][4096 + (wc * 64 + nf * 16 + l15) * 32 + lg * 8];
    #pragma unroll
    for (int mf = 0; mf < 4; ++mf)
      #pragma unroll
      for (int nf = 0; nf < 4; ++nf)
        acc[mf][nf] = __builtin_amdgcn_mfma_f32_16x16x32_bf16(af[mf], bfr[nf], acc[mf][nf], 0, 0, 0);

    __syncthreads();
    cur ^= 1;
  }

  #pragma unroll
  for (int mf = 0; mf < 4; ++mf) {
    #pragma unroll
    for (int nf = 0; nf < 4; ++nf) {
      const int col = n0 + wc * 64 + nf * 16 + l15;
      const float bv = bias[col];
      #pragma unroll
      for (int r = 0; r < 4; ++r) {
        const int row = m0 + wr * 64 + mf * 16 + lg * 4 + r;
        float val = acc[mf][nf][r] + bv;
        if (RELU) val = fmaxf(val, 0.f);
        if (OUT_BF16)
          ((unsigned short*)Cout)[(size_t)row * Nld + col] = f2bf(val);
        else
          ((float*)Cout)[(size_t)row * Nld + col] = val;
      }
    }
  }
}

// ---------------- flash attention on fused qkv buffer [M][3072] ----------------
__global__ __launch_bounds__(256) void attn_kernel(
    const unsigned short* __restrict__ qkv, unsigned short* __restrict__ ctx) {
  const int b = blockIdx.z, h = blockIdx.y;
  const int t = threadIdx.x, wave = t >> 6, lane = t & 63;
  const int l15 = lane & 15, lg = lane >> 4;
  const int qrow0 = blockIdx.x * 64 + wave * 16;
  const unsigned short* qbs = qkv + (size_t)b * SEQ * QKVLD + h * DHEAD;
  const unsigned short* kbs = qbs + EDIM;
  const unsigned short* vbs = qbs + 2 * EDIM;
  __shared__ unsigned short Ksm[32][72];
  __shared__ unsigned short VTs[64 * 32];
  __shared__ unsigned short p_lds[4][16][40];

  const unsigned short* qp = qbs + (size_t)(qrow0 + l15) * QKVLD + lg * 8;
  bf16x8 a0 = *(const bf16x8*)qp;
  bf16x8 a1 = *(const bf16x8*)(qp + 32);

  f32x4 o0 = {0,0,0,0}, o1 = {0,0,0,0}, o2 = {0,0,0,0}, o3 = {0,0,0,0};
  float m[4], ls[4];
  #pragma unroll
  for (int r = 0; r < 4; ++r) { m[r] = -1e30f; ls[r] = 0.f; }

  const int sr = t >> 3;
  const int sc = (t & 7) * 8;
  const unsigned short* kgp = kbs + (size_t)sr * QKVLD + sc;
  const unsigned short* vgp = vbs + (size_t)sr * QKVLD + sc;
  const size_t tilestep = (size_t)32 * QKVLD;

  s16x8 kreg = *(const s16x8*)kgp;
  s16x8 vreg = *(const s16x8*)vgp;
  const int xw = (sc >> 3) << 4;

  const int NT = SEQ / 32;
  for (int j = 0; j < NT; ++j) {
    *(s16x8*)&Ksm[sr][sc] = kreg;
    #pragma unroll
    for (int e = 0; e < 8; ++e) {
      const int byteo = (((sc + e) * 32 + sr) * 2) ^ xw;
      *(unsigned short*)((char*)VTs + byteo) = (unsigned short)vreg[e];
    }
    __syncthreads();

    bf16x8 b00 = *(const bf16x8*)&Ksm[l15][lg * 8];
    bf16x8 b01 = *(const bf16x8*)&Ksm[l15][32 + lg * 8];
    bf16x8 b10 = *(const bf16x8*)&Ksm[16 + l15][lg * 8];
    bf16x8 b11 = *(const bf16x8*)&Ksm[16 + l15][32 + lg * 8];
    f32x4 s0 = {0,0,0,0}, s1 = {0,0,0,0};
    __builtin_amdgcn_s_setprio(1);
    s0 = __builtin_amdgcn_mfma_f32_16x16x32_bf16(a0, b00, s0, 0, 0, 0);
    s0 = __builtin_amdgcn_mfma_f32_16x16x32_bf16(a1, b01, s0, 0, 0, 0);
    s1 = __builtin_amdgcn_mfma_f32_16x16x32_bf16(a0, b10, s1, 0, 0, 0);
    s1 = __builtin_amdgcn_mfma_f32_16x16x32_bf16(a1, b11, s1, 0, 0, 0);
    __builtin_amdgcn_s_setprio(0);

    if (j + 1 < NT) {
      kreg = *(const s16x8*)(kgp + (size_t)(j + 1) * tilestep);
      vreg = *(const s16x8*)(vgp + (size_t)(j + 1) * tilestep);
    }

    float mx[4], p0[4], p1[4], scl[4], rs[4];
    #pragma unroll
    for (int r = 0; r < 4; ++r) { s0[r] *= 0.125f; s1[r] *= 0.125f; mx[r] = fmaxf(s0[r], s1[r]); }
    #pragma unroll
    for (int off = 1; off < 16; off <<= 1) {
      #pragma unroll
      for (int r = 0; r < 4; ++r) mx[r] = fmaxf(mx[r], __shfl_xor(mx[r], off));
    }
    #pragma unroll
    for (int r = 0; r < 4; ++r) {
      const float mn = fmaxf(m[r], mx[r]);
      scl[r] = __expf(m[r] - mn);
      m[r] = mn;
      p0[r] = __expf(s0[r] - mn);
      p1[r] = __expf(s1[r] - mn);
      rs[r] = p0[r] + p1[r];
    }
    #pragma unroll
    for (int off = 1; off < 16; off <<= 1) {
      #pragma unroll
      for (int r = 0; r < 4; ++r) rs[r] += __shfl_xor(rs[r], off);
    }
    #pragma unroll
    for (int r = 0; r < 4; ++r) {
      ls[r] = ls[r] * scl[r] + rs[r];
      o0[r] *= scl[r]; o1[r] *= scl[r]; o2[r] *= scl[r]; o3[r] *= scl[r];
      p_lds[wave][lg * 4 + r][l15]      = f2bf(p0[r]);
      p_lds[wave][lg * 4 + r][16 + l15] = f2bf(p1[r]);
    }
    bf16x8 pa = *(const bf16x8*)&p_lds[wave][l15][lg * 8];

    auto vld = [&](int d0) {
      const int d = d0 + l15;
      const int byteo = ((d * 32 + lg * 8) * 2) ^ (((d >> 3) & 7) << 4);
      return *(const bf16x8*)((const char*)VTs + byteo);
    };
    bf16x8 v0 = vld(0), v1 = vld(16), v2 = vld(32), v3 = vld(48);
    __builtin_amdgcn_s_setprio(1);
    o0 = __builtin_amdgcn_mfma_f32_16x16x32_bf16(pa, v0, o0, 0, 0, 0);
    o1 = __builtin_amdgcn_mfma_f32_16x16x32_bf16(pa, v1, o1, 0, 0, 0);
    o2 = __builtin_amdgcn_mfma_f32_16x16x32_bf16(pa, v2, o2, 0, 0, 0);
    o3 = __builtin_amdgcn_mfma_f32_16x16x32_bf16(pa, v3, o3, 0, 0, 0);
    __builtin_amdgcn_s_setprio(0);
    __syncthreads();
  }

  unsigned short* cp = ctx + (size_t)b * SEQ * EDIM + h * DHEAD;
  #pragma unroll
  for (int r = 0; r < 4; ++r) {
    unsigned short* cr = cp + (size_t)(qrow0 + lg * 4 + r) * EDIM;
    const float inv = 1.f / ls[r];
    cr[l15]      = f2bf(o0[r] * inv);
    cr[16 + l15] = f2bf(o1[r] * inv);
    cr[32 + l15] = f2bf(o2[r] * inv);
    cr[48 + l15] = f2bf(o3[r] * inv);
  }
}

// ---------------- residual + layernorm ----------------
__global__ __launch_bounds__(256) void ln_add_kernel(
    const float* __restrict__ a, const float* __restrict__ g, const float* __restrict__ bb,
    float* __restrict__ x, unsigned short* __restrict__ xb) {
  const int row = blockIdx.x, t = threadIdx.x;
  const float* ar = a + (size_t)row * EDIM;
  float4 av = *(const float4*)(ar + t * 4);
  float s = av.x + av.y + av.z + av.w;
  float qq = av.x * av.x + av.y * av.y + av.z * av.z + av.w * av.w;
  #pragma unroll
  for (int off = 1; off < 64; off <<= 1) { s += __shfl_xor(s, off); qq += __shfl_xor(qq, off); }
  __shared__ float red[8];
  const int wv = t >> 6;
  if ((t & 63) == 0) { red[wv] = s; red[4 + wv] = qq; }
  __syncthreads();
  s = red[0] + red[1] + red[2] + red[3];
  qq = red[4] + red[5] + red[6] + red[7];
  const float mean = s * (1.f / EDIM);
  const float rstd = rsqrtf(qq * (1.f / EDIM) - mean * mean + EPSF);
  float4 gv = *(const float4*)(g + t * 4);
  float4 bv = *(const float4*)(bb + t * 4);
  float* xr = x + (size_t)row * EDIM;
  float4 xv = *(float4*)(xr + t * 4);
  float4 o;
  o.x = xv.x + (av.x - mean) * rstd * gv.x + bv.x;
  o.y = xv.y + (av.y - mean) * rstd * gv.y + bv.y;
  o.z = xv.z + (av.z - mean) * rstd * gv.z + bv.z;
  o.w = xv.w + (av.w - mean) * rstd * gv.w + bv.w;
  *(float4*)(xr + t * 4) = o;
  unsigned short* xbr = xb + (size_t)row * EDIM + t * 4;
  xbr[0] = f2bf(o.x); xbr[1] = f2bf(o.y); xbr[2] = f2bf(o.z); xbr[3] = f2bf(o.w);
}

// ---------------- final double layernorm -> bf16 ----------------
__global__ __launch_bounds__(256) void final_ln_kernel(
    const float* __restrict__ x, const float* __restrict__ g1, const float* __restrict__ b1,
    const float* __restrict__ g2, const float* __restrict__ b2,
    unsigned short* __restrict__ xb) {
  const int row = blockIdx.x, t = threadIdx.x;
  __shared__ float red[8];
  const int wv = t >> 6;
  const float* xr = x + (size_t)row * EDIM;
  float4 v = *(const float4*)(xr + t * 4);

  float s = v.x + v.y + v.z + v.w;
  float qq = v.x * v.x + v.y * v.y + v.z * v.z + v.w * v.w;
  #pragma unroll
  for (int off = 1; off < 64; off <<= 1) { s += __shfl_xor(s, off); qq += __shfl_xor(qq, off); }
  if ((t & 63) == 0) { red[wv] = s; red[4 + wv] = qq; }
  __syncthreads();
  s = red[0] + red[1] + red[2] + red[3];
  qq = red[4] + red[5] + red[6] + red[7];
  __syncthreads();
  float mean = s * (1.f / EDIM);
  float rstd = rsqrtf(qq * (1.f / EDIM) - mean * mean + EPSF);
  float4 g1v = *(const float4*)(g1 + t * 4);
  float4 b1v = *(const float4*)(b1 + t * 4);
  float4 tv;
  tv.x = (v.x - mean) * rstd * g1v.x + b1v.x;
  tv.y = (v.y - mean) * rstd * g1v.y + b1v.y;
  tv.z = (v.z - mean) * rstd * g1v.z + b1v.z;
  tv.w = (v.w - mean) * rstd * g1v.w + b1v.w;

  s = tv.x + tv.y + tv.z + tv.w;
  qq = tv.x * tv.x + tv.y * tv.y + tv.z * tv.z + tv.w * tv.w;
  #pragma unroll
  for (int off = 1; off < 64; off <<= 1) { s += __shfl_xor(s, off); qq += __shfl_xor(qq, off); }
  if ((t & 63) == 0) { red[wv] = s; red[4 + wv] = qq; }
  __syncthreads();
  s = red[0] + red[1] + red[2] + red[3];
  qq = red[4] + red[5] + red[6] + red[7];
  mean = s * (1.f / EDIM);
  rstd = rsqrtf(qq * (1.f / EDIM) - mean * mean + EPSF);
  float4 g2v = *(const float4*)(g2 + t * 4);
  float4 b2v = *(const float4*)(b2 + t * 4);
  unsigned short* o = xb + (size_t)row * EDIM + t * 4;
  o[0] = f2bf((tv.x - mean) * rstd * g2v.x + b2v.x);
  o[1] = f2bf((tv.y - mean) * rstd * g2v.y + b2v.y);
  o[2] = f2bf((tv.z - mean) * rstd * g2v.z + b2v.z);
  o[3] = f2bf((tv.w - mean) * rstd * g2v.w + b2v.w);
}

// ---------------- launch ----------------
extern "C" void kernel_launch(void* const* d_in, const int* in_sizes, int n_in,
                              void* d_out, int out_size, void* d_ws, size_t ws_size,
                              hipStream_t stream) {
  const int*   tokens = (const int*)d_in[0];
  const float* emb    = (const float*)d_in[1];
  const float* pe     = (const float*)d_in[2];
  const float* Wq     = (const float*)d_in[3];
  const float* Wk     = (const float*)d_in[4];
  const float* Wv     = (const float*)d_in[5];
  const float* Wo     = (const float*)d_in[6];
  const float* W1     = (const float*)d_in[7];
  const float* W2     = (const float*)d_in[8];
  const float* bq     = (const float*)d_in[9];
  const float* bk     = (const float*)d_in[10];
  const float* bv     = (const float*)d_in[11];
  const float* bo     = (const float*)d_in[12];
  const float* b1     = (const float*)d_in[13];
  const float* b2     = (const float*)d_in[14];
  const float* ln1_g  = (const float*)d_in[15];
  const float* ln1_b  = (const float*)d_in[16];
  const float* ln2_g  = (const float*)d_in[17];
  const float* ln2_b  = (const float*)d_in[18];
  const float* enc_g  = (const float*)d_in[19];
  const float* enc_b  = (const float*)d_in[20];
  const float* fin_g  = (const float*)d_in[21];
  const float* fin_b  = (const float*)d_in[22];
  const float* Wout   = (const float*)d_in[23];
  const float* bout   = (const float*)d_in[24];
  float* out = (float*)d_out;

  uint8_t* p = (uint8_t*)d_ws;
  auto alloc = [&](size_t bytes) {
    void* r = (void*)p;
    p += (bytes + 255) & ~(size_t)255;
    return r;
  };
  float*          x     = (float*)alloc((size_t)MROWS * EDIM * 4);
  unsigned short* xb    = (unsigned short*)alloc((size_t)MROWS * EDIM * 2);
  float*          tbuf  = (float*)alloc((size_t)MROWS * EDIM * 4);
  unsigned short* qkv   = (unsigned short*)alloc((size_t)MROWS * QKVLD * 2);
  unsigned short* ctx   = (unsigned short*)alloc((size_t)MROWS * EDIM * 2);
  unsigned short* wlt   = (unsigned short*)alloc((size_t)NLAYER * 12 * 1024 * 1024 * 2);
  unsigned short* woutt = (unsigned short*)alloc((size_t)VOCAB * EDIM * 2);
  float*          bqkv  = (float*)alloc((size_t)NLAYER * QKVLD * 4);
  unsigned short* ff1   = qkv;  // alias: qkv+ctx dead when ff1 is live
  if ((size_t)(p - (uint8_t*)d_ws) > ws_size) return;

  const dim3 blk(256);
  const dim3 blk512(512);
  const size_t LW = (size_t)12 * 1024 * 1024;
  const size_t M1 = 1024 * 1024;

  for (int i = 0; i < NLAYER; ++i) {
    unsigned short* lb = wlt + (size_t)i * LW;
    transpose_w<<<dim3(16, 16),  blk, 0, stream>>>(Wq + (size_t)i * M1, lb,          1024, 1024);
    transpose_w<<<dim3(16, 16),  blk, 0, stream>>>(Wk + (size_t)i * M1, lb + M1,     1024, 1024);
    transpose_w<<<dim3(16, 16),  blk, 0, stream>>>(Wv + (size_t)i * M1, lb + 2 * M1, 1024, 1024);
    transpose_w<<<dim3(16, 16),  blk, 0, stream>>>(Wo + (size_t)i * M1, lb + 3 * M1, 1024, 1024);
    transpose_w<<<dim3(16, 64),  blk, 0, stream>>>(W1 + (size_t)i * 4 * M1, lb + 4 * M1, 4096, 1024);
    transpose_w<<<dim3(64, 16),  blk, 0, stream>>>(W2 + (size_t)i * 4 * M1, lb + 8 * M1, 1024, 4096);
  }
  transpose_w<<<dim3(16, 500), blk, 0, stream>>>(Wout, woutt, VOCAB, 1024);
  pack_bias<<<(NLAYER * QKVLD + 255) / 256, blk, 0, stream>>>(bq, bk, bv, bqkv);

  embed_kernel<<<MROWS, blk, 0, stream>>>(tokens, emb, pe, x, xb);

  const int MB  = MROWS / 128;
  const int MB2 = MROWS / 256;
  for (int i = 0; i < NLAYER; ++i) {
    unsigned short* lb = wlt + (size_t)i * LW;
    gemm256<1, 0><<<MB2 * (QKVLD / 256), blk512, 0, stream>>>(
        xb, lb, bqkv + (size_t)i * QKVLD, qkv, QKVLD, EDIM, MB2);
    attn_kernel<<<dim3(SEQ / 64, NHEAD, BATCH), blk, 0, stream>>>(qkv, ctx);
    gemm_bt<0, 0><<<MB * (EDIM / 128), blk, 0, stream>>>(ctx, lb + 3 * M1, bo + i * EDIM, tbuf, EDIM, EDIM, MB);
    ln_add_kernel<<<MROWS, blk, 0, stream>>>(tbuf, ln1_g + i * EDIM, ln1_b + i * EDIM, x, xb);
    gemm256<1, 1><<<MB2 * (DFFDIM / 256), blk512, 0, stream>>>(
        xb, lb + 4 * M1, b1 + i * DFFDIM, ff1, DFFDIM, EDIM, MB2);
    gemm_bt<0, 0><<<MB * (EDIM / 128), blk, 0, stream>>>(ff1, lb + 8 * M1, b2 + i * EDIM, tbuf, EDIM, DFFDIM, MB);
    ln_add_kernel<<<MROWS, blk, 0, stream>>>(tbuf, ln2_g + i * EDIM, ln2_b + i * EDIM, x, xb);
  }

  final_ln_kernel<<<MROWS, blk, 0, stream>>>(x, enc_g, enc_b, fin_g, fin_b, xb);
  gemm256<0, 0><<<MB2 * (VOCAB / 256), blk512, 0, stream>>>(
      xb, woutt, bout, out, VOCAB, EDIM, MB2);
}

// Round 6
// 1639.064 us; speedup vs baseline: 1.9058x; 1.0776x over previous
//
#include <hip/hip_runtime.h>
#include <hip/hip_bf16.h>
#include <stdint.h>

#define EDIM 1024
#define DFFDIM 4096
#define NLAYER 4
#define BATCH 4
#define SEQ 1024
#define NHEAD 16
#define DHEAD 64
#define VOCAB 32000
#define MROWS (BATCH*SEQ)
#define QKVLD (3*EDIM)
#define EPSF 1e-6f

typedef float f32x4 __attribute__((ext_vector_type(4)));
typedef short s16x8 __attribute__((ext_vector_type(8)));
typedef __bf16 bf16x8 __attribute__((ext_vector_type(8)));

__device__ inline unsigned short f2bf(float f) {
  union { float f; uint32_t u; } v; v.f = f;
  uint32_t r = v.u + 0x7fffu + ((v.u >> 16) & 1u);
  return (unsigned short)(r >> 16);
}

__device__ __forceinline__ void gload16(const void* g, void* l) {
  __builtin_amdgcn_global_load_lds(
      (const __attribute__((address_space(1))) void*)g,
      (__attribute__((address_space(3))) void*)l, 16, 0, 0);
}

// ---------------- embedding + positional encoding ----------------
__global__ __launch_bounds__(256) void embed_kernel(
    const int* __restrict__ tokens, const float* __restrict__ emb,
    const float* __restrict__ pe, float* __restrict__ x,
    unsigned short* __restrict__ xb) {
  const int row = blockIdx.x;
  const int s = row & (SEQ - 1);
  const int tok = tokens[row];
  const int c = threadIdx.x * 4;
  float4 ev = *(const float4*)(emb + (size_t)tok * EDIM + c);
  float4 pv = *(const float4*)(pe + (size_t)s * EDIM + c);
  float4 o;
  o.x = ev.x + pv.x; o.y = ev.y + pv.y; o.z = ev.z + pv.z; o.w = ev.w + pv.w;
  *(float4*)(x + (size_t)row * EDIM + c) = o;
  unsigned short* xr = xb + (size_t)row * EDIM + c;
  xr[0] = f2bf(o.x); xr[1] = f2bf(o.y); xr[2] = f2bf(o.z); xr[3] = f2bf(o.w);
}

// ---------------- weight transpose+convert: src f32 [K,N] -> dst bf16 [N,K] ----------------
__global__ __launch_bounds__(256) void transpose_w(
    const float* __restrict__ src, unsigned short* __restrict__ dst,
    int N, int K) {
  __shared__ float tl[64][65];
  const int t = threadIdx.x;
  const int k0 = blockIdx.x * 64, n0 = blockIdx.y * 64;
  const int c = (t & 15) * 4, r0 = t >> 4;
  #pragma unroll
  for (int i = 0; i < 4; ++i) {
    const int r = r0 + i * 16;
    float4 v = *(const float4*)(src + (size_t)(k0 + r) * N + n0 + c);
    tl[r][c] = v.x; tl[r][c + 1] = v.y; tl[r][c + 2] = v.z; tl[r][c + 3] = v.w;
  }
  __syncthreads();
  #pragma unroll
  for (int i = 0; i < 4; ++i) {
    const int n = r0 + i * 16;
    uint2 o;
    o.x = (uint32_t)f2bf(tl[c + 0][n]) | ((uint32_t)f2bf(tl[c + 1][n]) << 16);
    o.y = (uint32_t)f2bf(tl[c + 2][n]) | ((uint32_t)f2bf(tl[c + 3][n]) << 16);
    *(uint2*)(dst + (size_t)(n0 + n) * K + k0 + c) = o;
  }
}

// ---------------- pack qkv bias ----------------
__global__ __launch_bounds__(256) void pack_bias(
    const float* __restrict__ bq, const float* __restrict__ bk,
    const float* __restrict__ bv, float* __restrict__ dst) {
  const int idx = blockIdx.x * 256 + threadIdx.x;
  if (idx >= NLAYER * QKVLD) return;
  const int layer = idx / QKVLD, c = idx % QKVLD;
  float v;
  if (c < 1024)      v = bq[layer * 1024 + c];
  else if (c < 2048) v = bk[layer * 1024 + c - 1024];
  else               v = bv[layer * 1024 + c - 2048];
  dst[idx] = v;
}

// ---------------- 8-phase 256x256 GEMM, BK=64, counted vmcnt (T2+T3+T4+T5) ----------------
// LDS 128KB = 2 dbuf x { A-lo | A-hi | B-lo | B-hi } of 16KB (128 rows x 64 cols bf16).
// Element (r,c) of a half at byte r*128 + ((2c) ^ ((r&7)<<4))  -> conflict-free b128 reads.
// Staging of tile t+1: A-lo@(t-1,ph3), A-hi@(t,ph0), B-lo@(t,ph1), B-hi@(t,ph2);
// single vmcnt(2) at (t,ph3) leaves A-lo(t+2) in flight.
template<int OUT_BF16, int RELU>
__global__ __launch_bounds__(512, 2) void gemm8p(
    const unsigned short* __restrict__ A, const unsigned short* __restrict__ Bt,
    const float* __restrict__ bias, void* __restrict__ Cout,
    int Nld, int K, int NBLK) {
  __shared__ __attribute__((aligned(16))) unsigned short sm[65536];  // 128 KB
  char* smb = (char*)sm;
  const int t = threadIdx.x, lane = t & 63;
  const int wave = t >> 6, wr = wave >> 2, wc = wave & 3;
  const int l15 = lane & 15, lg = lane >> 4;

  // XCD swizzle + n-fastest: consecutive co-XCD blocks share the A panel (L2-resident)
  const int cpx = gridDim.x >> 3;
  const int bid = blockIdx.x;
  const int swz = (bid & 7) * cpx + (bid >> 3);
  const int m0 = (swz / NBLK) * 256;
  const int n0 = (swz % NBLK) * 256;

  f32x4 acc[8][4];
  #pragma unroll
  for (int i = 0; i < 8; ++i)
    #pragma unroll
    for (int j = 0; j < 4; ++j)
      acc[i][j] = (f32x4){0.f, 0.f, 0.f, 0.f};

  // staging map: thread t covers rows (t>>3) and 64+(t>>3) of a half; col pre-swizzled
  const int sr8 = t >> 3;
  const int sxe = ((t & 7) * 8) ^ ((sr8 & 7) << 3);
  const unsigned short* agp = A  + (size_t)(m0 + sr8) * K + sxe;
  const unsigned short* bgp = Bt + (size_t)(n0 + sr8) * K + sxe;
  const size_t r64 = (size_t)64 * K, r128 = (size_t)128 * K;
  char* dst_t = smb + t * 16;

#define STAGE(dOff, opOff, h, k0) do { \
    const unsigned short* g_ = ((opOff) ? bgp : agp) + (size_t)(h) * r128 + (k0); \
    char* d_ = dst_t + (dOff) + (opOff) + (h) * 16384; \
    gload16(g_, d_); gload16(g_ + r64, d_ + 8192); } while (0)

  // read-side swizzled column bytes for kk=0/1
  const int cx0 = (lg * 16) ^ ((l15 & 7) << 4);
  const int cx1 = cx0 ^ 64;

#define DO_PHASE(dOff, mq, nq, STG, WT) do { \
    bf16x8 af_[4][2], bf_[2][2]; \
    const char* ab_ = smb + (dOff) + wr * 16384 + l15 * 128; \
    const char* bb_ = smb + (dOff) + 32768 + (wc >> 1) * 16384 + ((wc & 1) * 64 + l15) * 128; \
    _Pragma("unroll") for (int i_ = 0; i_ < 4; ++i_) { \
      af_[i_][0] = *(const bf16x8*)(ab_ + ((mq) * 4 + i_) * 2048 + cx0); \
      af_[i_][1] = *(const bf16x8*)(ab_ + ((mq) * 4 + i_) * 2048 + cx1); } \
    _Pragma("unroll") for (int j_ = 0; j_ < 2; ++j_) { \
      bf_[j_][0] = *(const bf16x8*)(bb_ + ((nq) * 2 + j_) * 2048 + cx0); \
      bf_[j_][1] = *(const bf16x8*)(bb_ + ((nq) * 2 + j_) * 2048 + cx1); } \
    STG; WT; \
    __builtin_amdgcn_s_barrier(); \
    asm volatile("s_waitcnt lgkmcnt(0)" ::: "memory"); \
    __builtin_amdgcn_sched_barrier(0); \
    __builtin_amdgcn_s_setprio(1); \
    _Pragma("unroll") for (int kk_ = 0; kk_ < 2; ++kk_) \
      _Pragma("unroll") for (int i_ = 0; i_ < 4; ++i_) \
        _Pragma("unroll") for (int j_ = 0; j_ < 2; ++j_) \
          acc[(mq) * 4 + i_][(nq) * 2 + j_] = __builtin_amdgcn_mfma_f32_16x16x32_bf16( \
              af_[i_][kk_], bf_[j_][kk_], acc[(mq) * 4 + i_][(nq) * 2 + j_], 0, 0, 0); \
    __builtin_amdgcn_s_setprio(0); \
    __builtin_amdgcn_sched_barrier(0); \
    __builtin_amdgcn_s_barrier(); \
  } while (0)

  const int NT = K / 64;
  // prologue: all 4 halves of tile 0 + A-lo of tile 1
  STAGE(0, 0, 0, 0);
  STAGE(0, 0, 1, 0);
  STAGE(0, 32768, 0, 0);
  STAGE(0, 32768, 1, 0);
  STAGE(65536, 0, 0, 64);
  asm volatile("s_waitcnt vmcnt(2)" ::: "memory");
  __builtin_amdgcn_s_barrier();

  for (int tt = 0; tt < NT; ++tt) {
    const int dc = (tt & 1) << 16;
    const int dn = dc ^ 65536;
    const int k1 = (tt + 1) * 64, k2 = (tt + 2) * 64;
    const bool s1 = tt + 1 < NT, s2 = tt + 2 < NT;

    DO_PHASE(dc, 0, 0, { if (s1) STAGE(dn, 0, 1, k1); }, {});
    DO_PHASE(dc, 0, 1, { if (s1) STAGE(dn, 32768, 0, k1); }, {});
    DO_PHASE(dc, 1, 0, { if (s1) STAGE(dn, 32768, 1, k1); }, {});
    DO_PHASE(dc, 1, 1, { if (s2) STAGE(dc, 0, 0, k2); },
             { if (s1) { if (s2) asm volatile("s_waitcnt vmcnt(2)" ::: "memory");
                         else    asm volatile("s_waitcnt vmcnt(0)" ::: "memory"); } });
  }

  #pragma unroll
  for (int mf = 0; mf < 8; ++mf) {
    #pragma unroll
    for (int nf = 0; nf < 4; ++nf) {
      const int col = n0 + wc * 64 + nf * 16 + l15;
      const float bv = bias[col];
      #pragma unroll
      for (int r = 0; r < 4; ++r) {
        const int row = m0 + wr * 128 + mf * 16 + lg * 4 + r;
        float val = acc[mf][nf][r] + bv;
        if (RELU) val = fmaxf(val, 0.f);
        if (OUT_BF16)
          ((unsigned short*)Cout)[(size_t)row * Nld + col] = f2bf(val);
        else
          ((float*)Cout)[(size_t)row * Nld + col] = val;
      }
    }
  }
#undef DO_PHASE
#undef STAGE
}

// ---------------- 128x128 2-phase dbuf GEMM (N=1024 shapes) ----------------
template<int OUT_BF16, int RELU>
__global__ __launch_bounds__(256) void gemm_bt(
    const unsigned short* __restrict__ A, const unsigned short* __restrict__ Bt,
    const float* __restrict__ bias, void* __restrict__ Cout,
    int Nld, int K, int NBLK) {
  __shared__ unsigned short sm[2][8192];
  const int t = threadIdx.x, lane = t & 63;
  const int wave = t >> 6, wr = wave >> 1, wc = wave & 1;
  const int l15 = lane & 15, lg = lane >> 4;

  const int cpx = gridDim.x >> 3;
  const int bid = blockIdx.x;
  const int swz = (bid & 7) * cpx + (bid >> 3);
  const int m0 = (swz / NBLK) * 128;
  const int n0 = (swz % NBLK) * 128;

  f32x4 acc[4][4];
  #pragma unroll
  for (int i = 0; i < 4; ++i)
    #pragma unroll
    for (int j = 0; j < 4; ++j)
      acc[i][j] = (f32x4){0.f, 0.f, 0.f, 0.f};

  const int srow = wave * 32 + (lane >> 2);
  const int scol = (lane & 3) * 8;
  const unsigned short* agp = A + (size_t)(m0 + srow) * K + scol;
  const unsigned short* bgp = Bt + (size_t)(n0 + srow) * K + scol;
  const size_t rstep = (size_t)16 * K;
  const int loff = wave * 1024 + lane * 8;

  auto stage = [&](int buf, int k0) {
    unsigned short* l = &sm[buf][loff];
    gload16(agp + k0, l);
    gload16(agp + rstep + k0, l + 512);
    gload16(bgp + k0, l + 4096);
    gload16(bgp + rstep + k0, l + 4096 + 512);
  };

  stage(0, 0);
  __syncthreads();
  int cur = 0;
  for (int k0 = 0; k0 < K; k0 += 32) {
    if (k0 + 32 < K) stage(cur ^ 1, k0 + 32);

    bf16x8 af[4], bfr[4];
    #pragma unroll
    for (int mf = 0; mf < 4; ++mf)
      af[mf] = *(const bf16x8*)&sm[cur][(wr * 64 + mf * 16 + l15) * 32 + lg * 8];
    #pragma unroll
    for (int nf = 0; nf < 4; ++nf)
      bfr[nf] = *(const bf16x8*)&sm[cur][4096 + (wc * 64 + nf * 16 + l15) * 32 + lg * 8];
    #pragma unroll
    for (int mf = 0; mf < 4; ++mf)
      #pragma unroll
      for (int nf = 0; nf < 4; ++nf)
        acc[mf][nf] = __builtin_amdgcn_mfma_f32_16x16x32_bf16(af[mf], bfr[nf], acc[mf][nf], 0, 0, 0);

    __syncthreads();
    cur ^= 1;
  }

  #pragma unroll
  for (int mf = 0; mf < 4; ++mf) {
    #pragma unroll
    for (int nf = 0; nf < 4; ++nf) {
      const int col = n0 + wc * 64 + nf * 16 + l15;
      const float bv = bias[col];
      #pragma unroll
      for (int r = 0; r < 4; ++r) {
        const int row = m0 + wr * 64 + mf * 16 + lg * 4 + r;
        float val = acc[mf][nf][r] + bv;
        if (RELU) val = fmaxf(val, 0.f);
        if (OUT_BF16)
          ((unsigned short*)Cout)[(size_t)row * Nld + col] = f2bf(val);
        else
          ((float*)Cout)[(size_t)row * Nld + col] = val;
      }
    }
  }
}

// ---------------- flash attention, KVBLK=64, fused qkv buffer [M][3072] ----------------
__global__ __launch_bounds__(256) void attn_kernel(
    const unsigned short* __restrict__ qkv, unsigned short* __restrict__ ctx) {
  const int b = blockIdx.z, h = blockIdx.y;
  const int t = threadIdx.x, wave = t >> 6, lane = t & 63;
  const int l15 = lane & 15, lg = lane >> 4;
  const int qrow0 = blockIdx.x * 64 + wave * 16;
  const unsigned short* qbs = qkv + (size_t)b * SEQ * QKVLD + h * DHEAD;
  const unsigned short* kbs = qbs + EDIM;
  const unsigned short* vbs = qbs + 2 * EDIM;
  __shared__ unsigned short Ksm[64][72];     // 64 kv x 64 d (+8 pad)
  __shared__ unsigned short VTs[64 * 64];    // swizzled: byte = d*128 + ((kv*2) ^ ((d&7)<<4))
  __shared__ unsigned short p_lds[4][16][72];

  const unsigned short* qp = qbs + (size_t)(qrow0 + l15) * QKVLD + lg * 8;
  bf16x8 a0 = *(const bf16x8*)qp;
  bf16x8 a1 = *(const bf16x8*)(qp + 32);

  f32x4 o0 = {0,0,0,0}, o1 = {0,0,0,0}, o2 = {0,0,0,0}, o3 = {0,0,0,0};
  float m[4], ls[4];
  #pragma unroll
  for (int r = 0; r < 4; ++r) { m[r] = -1e30f; ls[r] = 0.f; }

  const int sr = t >> 2;            // kv row 0..63
  const int sc = (t & 3) * 16;      // d col {0,16,32,48}
  const unsigned short* kgp = kbs + (size_t)sr * QKVLD + sc;
  const unsigned short* vgp = vbs + (size_t)sr * QKVLD + sc;
  const size_t tilestep = (size_t)64 * QKVLD;

  s16x8 kr0 = *(const s16x8*)kgp, kr1 = *(const s16x8*)(kgp + 8);
  s16x8 vr0 = *(const s16x8*)vgp, vr1 = *(const s16x8*)(vgp + 8);

  const int NT = SEQ / 64;
  for (int j = 0; j < NT; ++j) {
    // write staged regs to LDS
    *(s16x8*)&Ksm[sr][sc] = kr0;
    *(s16x8*)&Ksm[sr][sc + 8] = kr1;
    #pragma unroll
    for (int c = 0; c < 2; ++c) {
      s16x8 vv = c ? vr1 : vr0;
      #pragma unroll
      for (int e = 0; e < 8; ++e) {
        const int d = sc + c * 8 + e;
        const int byteo = d * 128 + ((sr * 2) ^ (e << 4));
        *(unsigned short*)((char*)VTs + byteo) = (unsigned short)vv[e];
      }
    }
    __syncthreads();

    // QK^T: s[g] over kv groups g*16+l15
    f32x4 s[4];
    __builtin_amdgcn_s_setprio(1);
    #pragma unroll
    for (int g = 0; g < 4; ++g) {
      bf16x8 k0 = *(const bf16x8*)&Ksm[g * 16 + l15][lg * 8];
      bf16x8 k1 = *(const bf16x8*)&Ksm[g * 16 + l15][32 + lg * 8];
      f32x4 z = {0, 0, 0, 0};
      z = __builtin_amdgcn_mfma_f32_16x16x32_bf16(a0, k0, z, 0, 0, 0);
      s[g] = __builtin_amdgcn_mfma_f32_16x16x32_bf16(a1, k1, z, 0, 0, 0);
    }
    __builtin_amdgcn_s_setprio(0);

    // T14: prefetch next tile K/V to regs (hides HBM under softmax+PV)
    if (j + 1 < NT) {
      const unsigned short* kn = kgp + (size_t)(j + 1) * tilestep;
      const unsigned short* vn = vgp + (size_t)(j + 1) * tilestep;
      kr0 = *(const s16x8*)kn; kr1 = *(const s16x8*)(kn + 8);
      vr0 = *(const s16x8*)vn; vr1 = *(const s16x8*)(vn + 8);
    }

    float mx[4], scl[4], rs[4];
    #pragma unroll
    for (int g = 0; g < 4; ++g)
      #pragma unroll
      for (int r = 0; r < 4; ++r) s[g][r] *= 0.125f;
    #pragma unroll
    for (int r = 0; r < 4; ++r)
      mx[r] = fmaxf(fmaxf(s[0][r], s[1][r]), fmaxf(s[2][r], s[3][r]));
    #pragma unroll
    for (int off = 1; off < 16; off <<= 1) {
      #pragma unroll
      for (int r = 0; r < 4; ++r) mx[r] = fmaxf(mx[r], __shfl_xor(mx[r], off));
    }
    #pragma unroll
    for (int r = 0; r < 4; ++r) {
      const float mn = fmaxf(m[r], mx[r]);
      scl[r] = __expf(m[r] - mn);
      m[r] = mn;
    }
    #pragma unroll
    for (int g = 0; g < 4; ++g)
      #pragma unroll
      for (int r = 0; r < 4; ++r) s[g][r] = __expf(s[g][r] - m[r]);
    #pragma unroll
    for (int r = 0; r < 4; ++r)
      rs[r] = (s[0][r] + s[1][r]) + (s[2][r] + s[3][r]);
    #pragma unroll
    for (int off = 1; off < 16; off <<= 1) {
      #pragma unroll
      for (int r = 0; r < 4; ++r) rs[r] += __shfl_xor(rs[r], off);
    }
    #pragma unroll
    for (int r = 0; r < 4; ++r) {
      ls[r] = ls[r] * scl[r] + rs[r];
      o0[r] *= scl[r]; o1[r] *= scl[r]; o2[r] *= scl[r]; o3[r] *= scl[r];
      #pragma unroll
      for (int g = 0; g < 4; ++g)
        p_lds[wave][lg * 4 + r][g * 16 + l15] = f2bf(s[g][r]);
    }
    bf16x8 pa0 = *(const bf16x8*)&p_lds[wave][l15][lg * 8];
    bf16x8 pa1 = *(const bf16x8*)&p_lds[wave][l15][32 + lg * 8];

    auto vld = [&](int dg, int c) {
      const int byteo = (dg * 16 + l15) * 128 + ((c * 64 + lg * 16) ^ ((l15 & 7) << 4));
      return *(const bf16x8*)((const char*)VTs + byteo);
    };
    __builtin_amdgcn_s_setprio(1);
    o0 = __builtin_amdgcn_mfma_f32_16x16x32_bf16(pa0, vld(0, 0), o0, 0, 0, 0);
    o1 = __builtin_amdgcn_mfma_f32_16x16x32_bf16(pa0, vld(1, 0), o1, 0, 0, 0);
    o2 = __builtin_amdgcn_mfma_f32_16x16x32_bf16(pa0, vld(2, 0), o2, 0, 0, 0);
    o3 = __builtin_amdgcn_mfma_f32_16x16x32_bf16(pa0, vld(3, 0), o3, 0, 0, 0);
    o0 = __builtin_amdgcn_mfma_f32_16x16x32_bf16(pa1, vld(0, 1), o0, 0, 0, 0);
    o1 = __builtin_amdgcn_mfma_f32_16x16x32_bf16(pa1, vld(1, 1), o1, 0, 0, 0);
    o2 = __builtin_amdgcn_mfma_f32_16x16x32_bf16(pa1, vld(2, 1), o2, 0, 0, 0);
    o3 = __builtin_amdgcn_mfma_f32_16x16x32_bf16(pa1, vld(3, 1), o3, 0, 0, 0);
    __builtin_amdgcn_s_setprio(0);
    __syncthreads();
  }

  unsigned short* cp = ctx + (size_t)b * SEQ * EDIM + h * DHEAD;
  #pragma unroll
  for (int r = 0; r < 4; ++r) {
    unsigned short* cr = cp + (size_t)(qrow0 + lg * 4 + r) * EDIM;
    const float inv = 1.f / ls[r];
    cr[l15]      = f2bf(o0[r] * inv);
    cr[16 + l15] = f2bf(o1[r] * inv);
    cr[32 + l15] = f2bf(o2[r] * inv);
    cr[48 + l15] = f2bf(o3[r] * inv);
  }
}

// ---------------- residual + layernorm ----------------
__global__ __launch_bounds__(256) void ln_add_kernel(
    const float* __restrict__ a, const float* __restrict__ g, const float* __restrict__ bb,
    float* __restrict__ x, unsigned short* __restrict__ xb) {
  const int row = blockIdx.x, t = threadIdx.x;
  const float* ar = a + (size_t)row * EDIM;
  float4 av = *(const float4*)(ar + t * 4);
  float s = av.x + av.y + av.z + av.w;
  float qq = av.x * av.x + av.y * av.y + av.z * av.z + av.w * av.w;
  #pragma unroll
  for (int off = 1; off < 64; off <<= 1) { s += __shfl_xor(s, off); qq += __shfl_xor(qq, off); }
  __shared__ float red[8];
  const int wv = t >> 6;
  if ((t & 63) == 0) { red[wv] = s; red[4 + wv] = qq; }
  __syncthreads();
  s = red[0] + red[1] + red[2] + red[3];
  qq = red[4] + red[5] + red[6] + red[7];
  const float mean = s * (1.f / EDIM);
  const float rstd = rsqrtf(qq * (1.f / EDIM) - mean * mean + EPSF);
  float4 gv = *(const float4*)(g + t * 4);
  float4 bv = *(const float4*)(bb + t * 4);
  float* xr = x + (size_t)row * EDIM;
  float4 xv = *(float4*)(xr + t * 4);
  float4 o;
  o.x = xv.x + (av.x - mean) * rstd * gv.x + bv.x;
  o.y = xv.y + (av.y - mean) * rstd * gv.y + bv.y;
  o.z = xv.z + (av.z - mean) * rstd * gv.z + bv.z;
  o.w = xv.w + (av.w - mean) * rstd * gv.w + bv.w;
  *(float4*)(xr + t * 4) = o;
  unsigned short* xbr = xb + (size_t)row * EDIM + t * 4;
  xbr[0] = f2bf(o.x); xbr[1] = f2bf(o.y); xbr[2] = f2bf(o.z); xbr[3] = f2bf(o.w);
}

// ---------------- final double layernorm -> bf16 ----------------
__global__ __launch_bounds__(256) void final_ln_kernel(
    const float* __restrict__ x, const float* __restrict__ g1, const float* __restrict__ b1,
    const float* __restrict__ g2, const float* __restrict__ b2,
    unsigned short* __restrict__ xb) {
  const int row = blockIdx.x, t = threadIdx.x;
  __shared__ float red[8];
  const int wv = t >> 6;
  const float* xr = x + (size_t)row * EDIM;
  float4 v = *(const float4*)(xr + t * 4);

  float s = v.x + v.y + v.z + v.w;
  float qq = v.x * v.x + v.y * v.y + v.z * v.z + v.w * v.w;
  #pragma unroll
  for (int off = 1; off < 64; off <<= 1) { s += __shfl_xor(s, off); qq += __shfl_xor(qq, off); }
  if ((t & 63) == 0) { red[wv] = s; red[4 + wv] = qq; }
  __syncthreads();
  s = red[0] + red[1] + red[2] + red[3];
  qq = red[4] + red[5] + red[6] + red[7];
  __syncthreads();
  float mean = s * (1.f / EDIM);
  float rstd = rsqrtf(qq * (1.f / EDIM) - mean * mean + EPSF);
  float4 g1v = *(const float4*)(g1 + t * 4);
  float4 b1v = *(const float4*)(b1 + t * 4);
  float4 tv;
  tv.x = (v.x - mean) * rstd * g1v.x + b1v.x;
  tv.y = (v.y - mean) * rstd * g1v.y + b1v.y;
  tv.z = (v.z - mean) * rstd * g1v.z + b1v.z;
  tv.w = (v.w - mean) * rstd * g1v.w + b1v.w;

  s = tv.x + tv.y + tv.z + tv.w;
  qq = tv.x * tv.x + tv.y * tv.y + tv.z * tv.z + tv.w * tv.w;
  #pragma unroll
  for (int off = 1; off < 64; off <<= 1) { s += __shfl_xor(s, off); qq += __shfl_xor(qq, off); }
  if ((t & 63) == 0) { red[wv] = s; red[4 + wv] = qq; }
  __syncthreads();
  s = red[0] + red[1] + red[2] + red[3];
  qq = red[4] + red[5] + red[6] + red[7];
  mean = s * (1.f / EDIM);
  rstd = rsqrtf(qq * (1.f / EDIM) - mean * mean + EPSF);
  float4 g2v = *(const float4*)(g2 + t * 4);
  float4 b2v = *(const float4*)(b2 + t * 4);
  unsigned short* o = xb + (size_t)row * EDIM + t * 4;
  o[0] = f2bf((tv.x - mean) * rstd * g2v.x + b2v.x);
  o[1] = f2bf((tv.y - mean) * rstd * g2v.y + b2v.y);
  o[2] = f2bf((tv.z - mean) * rstd * g2v.z + b2v.z);
  o[3] = f2bf((tv.w - mean) * rstd * g2v.w + b2v.w);
}

// ---------------- launch ----------------
extern "C" void kernel_launch(void* const* d_in, const int* in_sizes, int n_in,
                              void* d_out, int out_size, void* d_ws, size_t ws_size,
                              hipStream_t stream) {
  const int*   tokens = (const int*)d_in[0];
  const float* emb    = (const float*)d_in[1];
  const float* pe     = (const float*)d_in[2];
  const float* Wq     = (const float*)d_in[3];
  const float* Wk     = (const float*)d_in[4];
  const float* Wv     = (const float*)d_in[5];
  const float* Wo     = (const float*)d_in[6];
  const float* W1     = (const float*)d_in[7];
  const float* W2     = (const float*)d_in[8];
  const float* bq     = (const float*)d_in[9];
  const float* bk     = (const float*)d_in[10];
  const float* bv     = (const float*)d_in[11];
  const float* bo     = (const float*)d_in[12];
  const float* b1     = (const float*)d_in[13];
  const float* b2     = (const float*)d_in[14];
  const float* ln1_g  = (const float*)d_in[15];
  const float* ln1_b  = (const float*)d_in[16];
  const float* ln2_g  = (const float*)d_in[17];
  const float* ln2_b  = (const float*)d_in[18];
  const float* enc_g  = (const float*)d_in[19];
  const float* enc_b  = (const float*)d_in[20];
  const float* fin_g  = (const float*)d_in[21];
  const float* fin_b  = (const float*)d_in[22];
  const float* Wout   = (const float*)d_in[23];
  const float* bout   = (const float*)d_in[24];
  float* out = (float*)d_out;

  uint8_t* p = (uint8_t*)d_ws;
  auto alloc = [&](size_t bytes) {
    void* r = (void*)p;
    p += (bytes + 255) & ~(size_t)255;
    return r;
  };
  float*          x     = (float*)alloc((size_t)MROWS * EDIM * 4);
  unsigned short* xb    = (unsigned short*)alloc((size_t)MROWS * EDIM * 2);
  float*          tbuf  = (float*)alloc((size_t)MROWS * EDIM * 4);
  unsigned short* qkv   = (unsigned short*)alloc((size_t)MROWS * QKVLD * 2);
  unsigned short* ctx   = (unsigned short*)alloc((size_t)MROWS * EDIM * 2);
  unsigned short* wlt   = (unsigned short*)alloc((size_t)NLAYER * 12 * 1024 * 1024 * 2);
  unsigned short* woutt = (unsigned short*)alloc((size_t)VOCAB * EDIM * 2);
  float*          bqkv  = (float*)alloc((size_t)NLAYER * QKVLD * 4);
  unsigned short* ff1   = qkv;  // alias: qkv+ctx dead when ff1 is live
  if ((size_t)(p - (uint8_t*)d_ws) > ws_size) return;

  const dim3 blk(256);
  const dim3 blk512(512);
  const size_t LW = (size_t)12 * 1024 * 1024;
  const size_t M1 = 1024 * 1024;

  for (int i = 0; i < NLAYER; ++i) {
    unsigned short* lb = wlt + (size_t)i * LW;
    transpose_w<<<dim3(16, 16),  blk, 0, stream>>>(Wq + (size_t)i * M1, lb,          1024, 1024);
    transpose_w<<<dim3(16, 16),  blk, 0, stream>>>(Wk + (size_t)i * M1, lb + M1,     1024, 1024);
    transpose_w<<<dim3(16, 16),  blk, 0, stream>>>(Wv + (size_t)i * M1, lb + 2 * M1, 1024, 1024);
    transpose_w<<<dim3(16, 16),  blk, 0, stream>>>(Wo + (size_t)i * M1, lb + 3 * M1, 1024, 1024);
    transpose_w<<<dim3(16, 64),  blk, 0, stream>>>(W1 + (size_t)i * 4 * M1, lb + 4 * M1, 4096, 1024);
    transpose_w<<<dim3(64, 16),  blk, 0, stream>>>(W2 + (size_t)i * 4 * M1, lb + 8 * M1, 1024, 4096);
  }
  transpose_w<<<dim3(16, 500), blk, 0, stream>>>(Wout, woutt, VOCAB, 1024);
  pack_bias<<<(NLAYER * QKVLD + 255) / 256, blk, 0, stream>>>(bq, bk, bv, bqkv);

  embed_kernel<<<MROWS, blk, 0, stream>>>(tokens, emb, pe, x, xb);

  const int MB2 = MROWS / 256;
  for (int i = 0; i < NLAYER; ++i) {
    unsigned short* lb = wlt + (size_t)i * LW;
    gemm8p<1, 0><<<MB2 * (QKVLD / 256), blk512, 0, stream>>>(
        xb, lb, bqkv + (size_t)i * QKVLD, qkv, QKVLD, EDIM, QKVLD / 256);
    attn_kernel<<<dim3(SEQ / 64, NHEAD, BATCH), blk, 0, stream>>>(qkv, ctx);
    gemm_bt<0, 0><<<(MROWS / 128) * (EDIM / 128), blk, 0, stream>>>(
        ctx, lb + 3 * M1, bo + i * EDIM, tbuf, EDIM, EDIM, EDIM / 128);
    ln_add_kernel<<<MROWS, blk, 0, stream>>>(tbuf, ln1_g + i * EDIM, ln1_b + i * EDIM, x, xb);
    gemm8p<1, 1><<<MB2 * (DFFDIM / 256), blk512, 0, stream>>>(
        xb, lb + 4 * M1, b1 + i * DFFDIM, ff1, DFFDIM, EDIM, DFFDIM / 256);
    gemm_bt<0, 0><<<(MROWS / 128) * (EDIM / 128), blk, 0, stream>>>(
        ff1, lb + 8 * M1, b2 + i * EDIM, tbuf, EDIM, DFFDIM, EDIM / 128);
    ln_add_kernel<<<MROWS, blk, 0, stream>>>(tbuf, ln2_g + i * EDIM, ln2_b + i * EDIM, x, xb);
  }

  final_ln_kernel<<<MROWS, blk, 0, stream>>>(x, enc_g, enc_b, fin_g, fin_b, xb);
  gemm8p<0, 0><<<MB2 * (VOCAB / 256), blk512, 0, stream>>>(
      xb, woutt, bout, out, VOCAB, EDIM, VOCAB / 256);
}

// Round 7
// 1434.757 us; speedup vs baseline: 2.1771x; 1.1424x over previous
//
#include <hip/hip_runtime.h>
#include <hip/hip_bf16.h>
#include <stdint.h>

#define EDIM 1024
#define DFFDIM 4096
#define NLAYER 4
#define BATCH 4
#define SEQ 1024
#define NHEAD 16
#define DHEAD 64
#define VOCAB 32000
#define MROWS (BATCH*SEQ)
#define QKVLD (3*EDIM)
#define EPSF 1e-6f

typedef float f32x4 __attribute__((ext_vector_type(4)));
typedef short s16x8 __attribute__((ext_vector_type(8)));
typedef __bf16 bf16x8 __attribute__((ext_vector_type(8)));

__device__ inline unsigned short f2bf(float f) {
  union { float f; uint32_t u; } v; v.f = f;
  uint32_t r = v.u + 0x7fffu + ((v.u >> 16) & 1u);
  return (unsigned short)(r >> 16);
}

__device__ __forceinline__ void gload16(const void* g, void* l) {
  __builtin_amdgcn_global_load_lds(
      (const __attribute__((address_space(1))) void*)g,
      (__attribute__((address_space(3))) void*)l, 16, 0, 0);
}

// ---------------- embedding + positional encoding ----------------
__global__ __launch_bounds__(256) void embed_kernel(
    const int* __restrict__ tokens, const float* __restrict__ emb,
    const float* __restrict__ pe, float* __restrict__ x,
    unsigned short* __restrict__ xb) {
  const int row = blockIdx.x;
  const int s = row & (SEQ - 1);
  const int tok = tokens[row];
  const int c = threadIdx.x * 4;
  float4 ev = *(const float4*)(emb + (size_t)tok * EDIM + c);
  float4 pv = *(const float4*)(pe + (size_t)s * EDIM + c);
  float4 o;
  o.x = ev.x + pv.x; o.y = ev.y + pv.y; o.z = ev.z + pv.z; o.w = ev.w + pv.w;
  *(float4*)(x + (size_t)row * EDIM + c) = o;
  unsigned short* xr = xb + (size_t)row * EDIM + c;
  xr[0] = f2bf(o.x); xr[1] = f2bf(o.y); xr[2] = f2bf(o.z); xr[3] = f2bf(o.w);
}

// ---------------- weight transpose+convert: src f32 [K,N] -> dst bf16 [N,K] ----------------
__global__ __launch_bounds__(256) void transpose_w(
    const float* __restrict__ src, unsigned short* __restrict__ dst,
    int N, int K) {
  __shared__ float tl[64][65];
  const int t = threadIdx.x;
  const int k0 = blockIdx.x * 64, n0 = blockIdx.y * 64;
  const int c = (t & 15) * 4, r0 = t >> 4;
  #pragma unroll
  for (int i = 0; i < 4; ++i) {
    const int r = r0 + i * 16;
    float4 v = *(const float4*)(src + (size_t)(k0 + r) * N + n0 + c);
    tl[r][c] = v.x; tl[r][c + 1] = v.y; tl[r][c + 2] = v.z; tl[r][c + 3] = v.w;
  }
  __syncthreads();
  #pragma unroll
  for (int i = 0; i < 4; ++i) {
    const int n = r0 + i * 16;
    uint2 o;
    o.x = (uint32_t)f2bf(tl[c + 0][n]) | ((uint32_t)f2bf(tl[c + 1][n]) << 16);
    o.y = (uint32_t)f2bf(tl[c + 2][n]) | ((uint32_t)f2bf(tl[c + 3][n]) << 16);
    *(uint2*)(dst + (size_t)(n0 + n) * K + k0 + c) = o;
  }
}

// ---------------- pack qkv bias ----------------
__global__ __launch_bounds__(256) void pack_bias(
    const float* __restrict__ bq, const float* __restrict__ bk,
    const float* __restrict__ bv, float* __restrict__ dst) {
  const int idx = blockIdx.x * 256 + threadIdx.x;
  if (idx >= NLAYER * QKVLD) return;
  const int layer = idx / QKVLD, c = idx % QKVLD;
  float v;
  if (c < 1024)      v = bq[layer * 1024 + c];
  else if (c < 2048) v = bk[layer * 1024 + c - 1024];
  else               v = bv[layer * 1024 + c - 2048];
  dst[idx] = v;
}

// ---------------- 3-deep pipelined GEMM, BK=32, 1 barrier/tile, counted vmcnt ----------------
// BM x BM tile, BM*2 threads. Per K-tile: 12 (BM=256) / 8 (BM=128) ds_read_b128 per wave
// (each fragment read ONCE), 4 gload_lds staging tile t+2, vmcnt(4), one s_barrier.
// LDS elem (r,c) at byte r*64 + ((2c) ^ (((r>>1)&3)<<4)) -> conflict-free b128 (r5/r6: 0 conflicts).
template<int BM, int OUT_BF16, int RELU>
__global__ __launch_bounds__(BM * 2, (BM == 256) ? 2 : 3) void gemm3(
    const unsigned short* __restrict__ A, const unsigned short* __restrict__ Bt,
    const float* __restrict__ bias, void* __restrict__ Cout,
    int Nld, int K, int NBLK) {
  constexpr int BUFB = BM * 128;          // bytes per LDS buffer (A half + B half)
  constexpr int ABYTES = BM * 64;         // bytes of the A sub-tile per buffer
  constexpr int WN = (BM == 256) ? 4 : 2; // waves along n
  constexpr int MF = BM / 32;             // 16-row m-frags per wave
  __shared__ __attribute__((aligned(16))) char smb[3 * BUFB];
  const int t = threadIdx.x, lane = t & 63;
  const int wave = t >> 6;
  const int wr = wave / WN, wc = wave % WN;
  const int l15 = lane & 15, lg = lane >> 4;

  // bijective XCD swizzle, n-fastest (co-XCD blocks share the A panel)
  const int cpx = gridDim.x >> 3;
  const int bid = blockIdx.x;
  const int swz = (bid & 7) * cpx + (bid >> 3);
  const int m0 = (swz / NBLK) * BM;
  const int n0 = (swz % NBLK) * BM;

  f32x4 acc[MF][4];
  #pragma unroll
  for (int i = 0; i < MF; ++i)
    #pragma unroll
    for (int j = 0; j < 4; ++j)
      acc[i][j] = (f32x4){0.f, 0.f, 0.f, 0.f};

  // staging: thread t -> rows (t>>2) and BM/2+(t>>2); source col pre-swizzled (G21)
  const int srow = t >> 2;
  const int scol = (((t & 3) ^ ((t >> 3) & 3)) << 3);
  const unsigned short* agp = A  + (size_t)(m0 + srow) * K + scol;
  const unsigned short* bgp = Bt + (size_t)(n0 + srow) * K + scol;
  const size_t rhalf = (size_t)(BM / 2) * K;

  // read-side swizzled offsets
  const int cxo = (lg * 16) ^ (((l15 >> 1) & 3) << 4);
  const int rdA = (wr * (BM / 2) + l15) * 64 + cxo;
  const int rdB = ABYTES + (wc * 64 + l15) * 64 + cxo;

  auto stage_tile = [&](int b, int kt) {
    const int k0 = kt * 32;
    char* d = smb + b * BUFB + t * 16;
    gload16(agp + k0, d);
    gload16(agp + rhalf + k0, d + BM * 32);
    gload16(bgp + k0, d + ABYTES);
    gload16(bgp + rhalf + k0, d + ABYTES + BM * 32);
  };

  const int NT = K / 32;
  stage_tile(0, 0);
  stage_tile(1, 1);
  asm volatile("s_waitcnt vmcnt(4)" ::: "memory");   // tile 0 landed; tile 1 in flight
  __builtin_amdgcn_s_barrier();
  __builtin_amdgcn_sched_barrier(0);

  int bufc = 0, bufn = 2;
  for (int tt = 0; tt < NT; ++tt) {
    if (tt + 2 < NT) stage_tile(bufn, tt + 2);

    const char* ab = smb + bufc * BUFB;
    bf16x8 af[MF], bf[4];
    #pragma unroll
    for (int mf = 0; mf < MF; ++mf)
      af[mf] = *(const bf16x8*)(ab + rdA + mf * 1024);
    #pragma unroll
    for (int nf = 0; nf < 4; ++nf)
      bf[nf] = *(const bf16x8*)(ab + rdB + nf * 1024);

    __builtin_amdgcn_s_setprio(1);
    #pragma unroll
    for (int mf = 0; mf < MF; ++mf)
      #pragma unroll
      for (int nf = 0; nf < 4; ++nf)
        acc[mf][nf] = __builtin_amdgcn_mfma_f32_16x16x32_bf16(af[mf], bf[nf], acc[mf][nf], 0, 0, 0);
    __builtin_amdgcn_s_setprio(0);

    if (tt + 2 < NT)      asm volatile("s_waitcnt vmcnt(4)" ::: "memory");  // t+1 done, t+2 in flight
    else if (tt + 1 < NT) asm volatile("s_waitcnt vmcnt(0)" ::: "memory");  // tail drain
    __builtin_amdgcn_sched_barrier(0);
    __builtin_amdgcn_s_barrier();
    __builtin_amdgcn_sched_barrier(0);

    bufc = (bufc == 2) ? 0 : bufc + 1;
    bufn = (bufn == 2) ? 0 : bufn + 1;
  }

  #pragma unroll
  for (int mf = 0; mf < MF; ++mf) {
    #pragma unroll
    for (int nf = 0; nf < 4; ++nf) {
      const int col = n0 + wc * 64 + nf * 16 + l15;
      const float bv = bias[col];
      #pragma unroll
      for (int r = 0; r < 4; ++r) {
        const int row = m0 + wr * (BM / 2) + mf * 16 + lg * 4 + r;
        float val = acc[mf][nf][r] + bv;
        if (RELU) val = fmaxf(val, 0.f);
        if (OUT_BF16)
          ((unsigned short*)Cout)[(size_t)row * Nld + col] = f2bf(val);
        else
          ((float*)Cout)[(size_t)row * Nld + col] = val;
      }
    }
  }
}

// ---------------- flash attention, KVBLK=64, fused qkv buffer [M][3072] ----------------
__global__ __launch_bounds__(256) void attn_kernel(
    const unsigned short* __restrict__ qkv, unsigned short* __restrict__ ctx) {
  const int b = blockIdx.z, h = blockIdx.y;
  const int t = threadIdx.x, wave = t >> 6, lane = t & 63;
  const int l15 = lane & 15, lg = lane >> 4;
  const int qrow0 = blockIdx.x * 64 + wave * 16;
  const unsigned short* qbs = qkv + (size_t)b * SEQ * QKVLD + h * DHEAD;
  const unsigned short* kbs = qbs + EDIM;
  const unsigned short* vbs = qbs + 2 * EDIM;
  __shared__ unsigned short Ksm[64][72];     // 64 kv x 64 d (+8 pad)
  __shared__ unsigned short VTs[64 * 64];    // swizzled: byte = d*128 + ((kv*2) ^ ((d&7)<<4))
  __shared__ unsigned short p_lds[4][16][72];

  const unsigned short* qp = qbs + (size_t)(qrow0 + l15) * QKVLD + lg * 8;
  bf16x8 a0 = *(const bf16x8*)qp;
  bf16x8 a1 = *(const bf16x8*)(qp + 32);

  f32x4 o0 = {0,0,0,0}, o1 = {0,0,0,0}, o2 = {0,0,0,0}, o3 = {0,0,0,0};
  float m[4], ls[4];
  #pragma unroll
  for (int r = 0; r < 4; ++r) { m[r] = -1e30f; ls[r] = 0.f; }

  const int sr = t >> 2;            // kv row 0..63
  const int sc = (t & 3) * 16;      // d col {0,16,32,48}
  const unsigned short* kgp = kbs + (size_t)sr * QKVLD + sc;
  const unsigned short* vgp = vbs + (size_t)sr * QKVLD + sc;
  const size_t tilestep = (size_t)64 * QKVLD;

  s16x8 kr0 = *(const s16x8*)kgp, kr1 = *(const s16x8*)(kgp + 8);
  s16x8 vr0 = *(const s16x8*)vgp, vr1 = *(const s16x8*)(vgp + 8);

  const int NT = SEQ / 64;
  for (int j = 0; j < NT; ++j) {
    *(s16x8*)&Ksm[sr][sc] = kr0;
    *(s16x8*)&Ksm[sr][sc + 8] = kr1;
    #pragma unroll
    for (int c = 0; c < 2; ++c) {
      s16x8 vv = c ? vr1 : vr0;
      #pragma unroll
      for (int e = 0; e < 8; ++e) {
        const int d = sc + c * 8 + e;
        const int byteo = d * 128 + ((sr * 2) ^ (e << 4));
        *(unsigned short*)((char*)VTs + byteo) = (unsigned short)vv[e];
      }
    }
    __syncthreads();

    f32x4 s[4];
    __builtin_amdgcn_s_setprio(1);
    #pragma unroll
    for (int g = 0; g < 4; ++g) {
      bf16x8 k0 = *(const bf16x8*)&Ksm[g * 16 + l15][lg * 8];
      bf16x8 k1 = *(const bf16x8*)&Ksm[g * 16 + l15][32 + lg * 8];
      f32x4 z = {0, 0, 0, 0};
      z = __builtin_amdgcn_mfma_f32_16x16x32_bf16(a0, k0, z, 0, 0, 0);
      s[g] = __builtin_amdgcn_mfma_f32_16x16x32_bf16(a1, k1, z, 0, 0, 0);
    }
    __builtin_amdgcn_s_setprio(0);

    if (j + 1 < NT) {
      const unsigned short* kn = kgp + (size_t)(j + 1) * tilestep;
      const unsigned short* vn = vgp + (size_t)(j + 1) * tilestep;
      kr0 = *(const s16x8*)kn; kr1 = *(const s16x8*)(kn + 8);
      vr0 = *(const s16x8*)vn; vr1 = *(const s16x8*)(vn + 8);
    }

    float mx[4], scl[4], rs[4];
    #pragma unroll
    for (int g = 0; g < 4; ++g)
      #pragma unroll
      for (int r = 0; r < 4; ++r) s[g][r] *= 0.125f;
    #pragma unroll
    for (int r = 0; r < 4; ++r)
      mx[r] = fmaxf(fmaxf(s[0][r], s[1][r]), fmaxf(s[2][r], s[3][r]));
    #pragma unroll
    for (int off = 1; off < 16; off <<= 1) {
      #pragma unroll
      for (int r = 0; r < 4; ++r) mx[r] = fmaxf(mx[r], __shfl_xor(mx[r], off));
    }
    #pragma unroll
    for (int r = 0; r < 4; ++r) {
      const float mn = fmaxf(m[r], mx[r]);
      scl[r] = __expf(m[r] - mn);
      m[r] = mn;
    }
    #pragma unroll
    for (int g = 0; g < 4; ++g)
      #pragma unroll
      for (int r = 0; r < 4; ++r) s[g][r] = __expf(s[g][r] - m[r]);
    #pragma unroll
    for (int r = 0; r < 4; ++r)
      rs[r] = (s[0][r] + s[1][r]) + (s[2][r] + s[3][r]);
    #pragma unroll
    for (int off = 1; off < 16; off <<= 1) {
      #pragma unroll
      for (int r = 0; r < 4; ++r) rs[r] += __shfl_xor(rs[r], off);
    }
    #pragma unroll
    for (int r = 0; r < 4; ++r) {
      ls[r] = ls[r] * scl[r] + rs[r];
      o0[r] *= scl[r]; o1[r] *= scl[r]; o2[r] *= scl[r]; o3[r] *= scl[r];
      #pragma unroll
      for (int g = 0; g < 4; ++g)
        p_lds[wave][lg * 4 + r][g * 16 + l15] = f2bf(s[g][r]);
    }
    bf16x8 pa0 = *(const bf16x8*)&p_lds[wave][l15][lg * 8];
    bf16x8 pa1 = *(const bf16x8*)&p_lds[wave][l15][32 + lg * 8];

    auto vld = [&](int dg, int c) {
      const int byteo = (dg * 16 + l15) * 128 + ((c * 64 + lg * 16) ^ ((l15 & 7) << 4));
      return *(const bf16x8*)((const char*)VTs + byteo);
    };
    __builtin_amdgcn_s_setprio(1);
    o0 = __builtin_amdgcn_mfma_f32_16x16x32_bf16(pa0, vld(0, 0), o0, 0, 0, 0);
    o1 = __builtin_amdgcn_mfma_f32_16x16x32_bf16(pa0, vld(1, 0), o1, 0, 0, 0);
    o2 = __builtin_amdgcn_mfma_f32_16x16x32_bf16(pa0, vld(2, 0), o2, 0, 0, 0);
    o3 = __builtin_amdgcn_mfma_f32_16x16x32_bf16(pa0, vld(3, 0), o3, 0, 0, 0);
    o0 = __builtin_amdgcn_mfma_f32_16x16x32_bf16(pa1, vld(0, 1), o0, 0, 0, 0);
    o1 = __builtin_amdgcn_mfma_f32_16x16x32_bf16(pa1, vld(1, 1), o1, 0, 0, 0);
    o2 = __builtin_amdgcn_mfma_f32_16x16x32_bf16(pa1, vld(2, 1), o2, 0, 0, 0);
    o3 = __builtin_amdgcn_mfma_f32_16x16x32_bf16(pa1, vld(3, 1), o3, 0, 0, 0);
    __builtin_amdgcn_s_setprio(0);
    __syncthreads();
  }

  unsigned short* cp = ctx + (size_t)b * SEQ * EDIM + h * DHEAD;
  #pragma unroll
  for (int r = 0; r < 4; ++r) {
    unsigned short* cr = cp + (size_t)(qrow0 + lg * 4 + r) * EDIM;
    const float inv = 1.f / ls[r];
    cr[l15]      = f2bf(o0[r] * inv);
    cr[16 + l15] = f2bf(o1[r] * inv);
    cr[32 + l15] = f2bf(o2[r] * inv);
    cr[48 + l15] = f2bf(o3[r] * inv);
  }
}

// ---------------- residual + layernorm ----------------
__global__ __launch_bounds__(256) void ln_add_kernel(
    const float* __restrict__ a, const float* __restrict__ g, const float* __restrict__ bb,
    float* __restrict__ x, unsigned short* __restrict__ xb) {
  const int row = blockIdx.x, t = threadIdx.x;
  const float* ar = a + (size_t)row * EDIM;
  float4 av = *(const float4*)(ar + t * 4);
  float s = av.x + av.y + av.z + av.w;
  float qq = av.x * av.x + av.y * av.y + av.z * av.z + av.w * av.w;
  #pragma unroll
  for (int off = 1; off < 64; off <<= 1) { s += __shfl_xor(s, off); qq += __shfl_xor(qq, off); }
  __shared__ float red[8];
  const int wv = t >> 6;
  if ((t & 63) == 0) { red[wv] = s; red[4 + wv] = qq; }
  __syncthreads();
  s = red[0] + red[1] + red[2] + red[3];
  qq = red[4] + red[5] + red[6] + red[7];
  const float mean = s * (1.f / EDIM);
  const float rstd = rsqrtf(qq * (1.f / EDIM) - mean * mean + EPSF);
  float4 gv = *(const float4*)(g + t * 4);
  float4 bv = *(const float4*)(bb + t * 4);
  float* xr = x + (size_t)row * EDIM;
  float4 xv = *(float4*)(xr + t * 4);
  float4 o;
  o.x = xv.x + (av.x - mean) * rstd * gv.x + bv.x;
  o.y = xv.y + (av.y - mean) * rstd * gv.y + bv.y;
  o.z = xv.z + (av.z - mean) * rstd * gv.z + bv.z;
  o.w = xv.w + (av.w - mean) * rstd * gv.w + bv.w;
  *(float4*)(xr + t * 4) = o;
  unsigned short* xbr = xb + (size_t)row * EDIM + t * 4;
  xbr[0] = f2bf(o.x); xbr[1] = f2bf(o.y); xbr[2] = f2bf(o.z); xbr[3] = f2bf(o.w);
}

// ---------------- final double layernorm -> bf16 ----------------
__global__ __launch_bounds__(256) void final_ln_kernel(
    const float* __restrict__ x, const float* __restrict__ g1, const float* __restrict__ b1,
    const float* __restrict__ g2, const float* __restrict__ b2,
    unsigned short* __restrict__ xb) {
  const int row = blockIdx.x, t = threadIdx.x;
  __shared__ float red[8];
  const int wv = t >> 6;
  const float* xr = x + (size_t)row * EDIM;
  float4 v = *(const float4*)(xr + t * 4);

  float s = v.x + v.y + v.z + v.w;
  float qq = v.x * v.x + v.y * v.y + v.z * v.z + v.w * v.w;
  #pragma unroll
  for (int off = 1; off < 64; off <<= 1) { s += __shfl_xor(s, off); qq += __shfl_xor(qq, off); }
  if ((t & 63) == 0) { red[wv] = s; red[4 + wv] = qq; }
  __syncthreads();
  s = red[0] + red[1] + red[2] + red[3];
  qq = red[4] + red[5] + red[6] + red[7];
  __syncthreads();
  float mean = s * (1.f / EDIM);
  float rstd = rsqrtf(qq * (1.f / EDIM) - mean * mean + EPSF);
  float4 g1v = *(const float4*)(g1 + t * 4);
  float4 b1v = *(const float4*)(b1 + t * 4);
  float4 tv;
  tv.x = (v.x - mean) * rstd * g1v.x + b1v.x;
  tv.y = (v.y - mean) * rstd * g1v.y + b1v.y;
  tv.z = (v.z - mean) * rstd * g1v.z + b1v.z;
  tv.w = (v.w - mean) * rstd * g1v.w + b1v.w;

  s = tv.x + tv.y + tv.z + tv.w;
  qq = tv.x * tv.x + tv.y * tv.y + tv.z * tv.z + tv.w * tv.w;
  #pragma unroll
  for (int off = 1; off < 64; off <<= 1) { s += __shfl_xor(s, off); qq += __shfl_xor(qq, off); }
  if ((t & 63) == 0) { red[wv] = s; red[4 + wv] = qq; }
  __syncthreads();
  s = red[0] + red[1] + red[2] + red[3];
  qq = red[4] + red[5] + red[6] + red[7];
  mean = s * (1.f / EDIM);
  rstd = rsqrtf(qq * (1.f / EDIM) - mean * mean + EPSF);
  float4 g2v = *(const float4*)(g2 + t * 4);
  float4 b2v = *(const float4*)(b2 + t * 4);
  unsigned short* o = xb + (size_t)row * EDIM + t * 4;
  o[0] = f2bf((tv.x - mean) * rstd * g2v.x + b2v.x);
  o[1] = f2bf((tv.y - mean) * rstd * g2v.y + b2v.y);
  o[2] = f2bf((tv.z - mean) * rstd * g2v.z + b2v.z);
  o[3] = f2bf((tv.w - mean) * rstd * g2v.w + b2v.w);
}

// ---------------- launch ----------------
extern "C" void kernel_launch(void* const* d_in, const int* in_sizes, int n_in,
                              void* d_out, int out_size, void* d_ws, size_t ws_size,
                              hipStream_t stream) {
  const int*   tokens = (const int*)d_in[0];
  const float* emb    = (const float*)d_in[1];
  const float* pe     = (const float*)d_in[2];
  const float* Wq     = (const float*)d_in[3];
  const float* Wk     = (const float*)d_in[4];
  const float* Wv     = (const float*)d_in[5];
  const float* Wo     = (const float*)d_in[6];
  const float* W1     = (const float*)d_in[7];
  const float* W2     = (const float*)d_in[8];
  const float* bq     = (const float*)d_in[9];
  const float* bk     = (const float*)d_in[10];
  const float* bv     = (const float*)d_in[11];
  const float* bo     = (const float*)d_in[12];
  const float* b1     = (const float*)d_in[13];
  const float* b2     = (const float*)d_in[14];
  const float* ln1_g  = (const float*)d_in[15];
  const float* ln1_b  = (const float*)d_in[16];
  const float* ln2_g  = (const float*)d_in[17];
  const float* ln2_b  = (const float*)d_in[18];
  const float* enc_g  = (const float*)d_in[19];
  const float* enc_b  = (const float*)d_in[20];
  const float* fin_g  = (const float*)d_in[21];
  const float* fin_b  = (const float*)d_in[22];
  const float* Wout   = (const float*)d_in[23];
  const float* bout   = (const float*)d_in[24];
  float* out = (float*)d_out;

  uint8_t* p = (uint8_t*)d_ws;
  auto alloc = [&](size_t bytes) {
    void* r = (void*)p;
    p += (bytes + 255) & ~(size_t)255;
    return r;
  };
  float*          x     = (float*)alloc((size_t)MROWS * EDIM * 4);
  unsigned short* xb    = (unsigned short*)alloc((size_t)MROWS * EDIM * 2);
  float*          tbuf  = (float*)alloc((size_t)MROWS * EDIM * 4);
  unsigned short* qkv   = (unsigned short*)alloc((size_t)MROWS * QKVLD * 2);
  unsigned short* ctx   = (unsigned short*)alloc((size_t)MROWS * EDIM * 2);
  unsigned short* wlt   = (unsigned short*)alloc((size_t)NLAYER * 12 * 1024 * 1024 * 2);
  unsigned short* woutt = (unsigned short*)alloc((size_t)VOCAB * EDIM * 2);
  float*          bqkv  = (float*)alloc((size_t)NLAYER * QKVLD * 4);
  unsigned short* ff1   = qkv;  // alias: qkv+ctx dead when ff1 is live
  if ((size_t)(p - (uint8_t*)d_ws) > ws_size) return;

  const dim3 blk(256);
  const dim3 blk512(512);
  const size_t LW = (size_t)12 * 1024 * 1024;
  const size_t M1 = 1024 * 1024;

  for (int i = 0; i < NLAYER; ++i) {
    unsigned short* lb = wlt + (size_t)i * LW;
    transpose_w<<<dim3(16, 16),  blk, 0, stream>>>(Wq + (size_t)i * M1, lb,          1024, 1024);
    transpose_w<<<dim3(16, 16),  blk, 0, stream>>>(Wk + (size_t)i * M1, lb + M1,     1024, 1024);
    transpose_w<<<dim3(16, 16),  blk, 0, stream>>>(Wv + (size_t)i * M1, lb + 2 * M1, 1024, 1024);
    transpose_w<<<dim3(16, 16),  blk, 0, stream>>>(Wo + (size_t)i * M1, lb + 3 * M1, 1024, 1024);
    transpose_w<<<dim3(16, 64),  blk, 0, stream>>>(W1 + (size_t)i * 4 * M1, lb + 4 * M1, 4096, 1024);
    transpose_w<<<dim3(64, 16),  blk, 0, stream>>>(W2 + (size_t)i * 4 * M1, lb + 8 * M1, 1024, 4096);
  }
  transpose_w<<<dim3(16, 500), blk, 0, stream>>>(Wout, woutt, VOCAB, 1024);
  pack_bias<<<(NLAYER * QKVLD + 255) / 256, blk, 0, stream>>>(bq, bk, bv, bqkv);

  embed_kernel<<<MROWS, blk, 0, stream>>>(tokens, emb, pe, x, xb);

  const int MB2 = MROWS / 256;   // 16
  const int MB1 = MROWS / 128;   // 32
  for (int i = 0; i < NLAYER; ++i) {
    unsigned short* lb = wlt + (size_t)i * LW;
    gemm3<256, 1, 0><<<MB2 * (QKVLD / 256), blk512, 0, stream>>>(
        xb, lb, bqkv + (size_t)i * QKVLD, qkv, QKVLD, EDIM, QKVLD / 256);
    attn_kernel<<<dim3(SEQ / 64, NHEAD, BATCH), blk, 0, stream>>>(qkv, ctx);
    gemm3<128, 0, 0><<<MB1 * (EDIM / 128), blk, 0, stream>>>(
        ctx, lb + 3 * M1, bo + i * EDIM, tbuf, EDIM, EDIM, EDIM / 128);
    ln_add_kernel<<<MROWS, blk, 0, stream>>>(tbuf, ln1_g + i * EDIM, ln1_b + i * EDIM, x, xb);
    gemm3<256, 1, 1><<<MB2 * (DFFDIM / 256), blk512, 0, stream>>>(
        xb, lb + 4 * M1, b1 + i * DFFDIM, ff1, DFFDIM, EDIM, DFFDIM / 256);
    gemm3<128, 0, 0><<<MB1 * (EDIM / 128), blk, 0, stream>>>(
        ff1, lb + 8 * M1, b2 + i * EDIM, tbuf, EDIM, DFFDIM, EDIM / 128);
    ln_add_kernel<<<MROWS, blk, 0, stream>>>(tbuf, ln2_g + i * EDIM, ln2_b + i * EDIM, x, xb);
  }

  final_ln_kernel<<<MROWS, blk, 0, stream>>>(x, enc_g, enc_b, fin_g, fin_b, xb);
  gemm3<256, 0, 0><<<MB2 * (VOCAB / 256), blk512, 0, stream>>>(
      xb, woutt, bout, out, VOCAB, EDIM, VOCAB / 256);
}